// Round 8
// baseline (745.448 us; speedup 1.0000x reference)
//
#include <hip/hip_runtime.h>
#include <hip/hip_bf16.h>
#include <stdint.h>

#define N_LEVELS   16
#define LOG2_T     19
#define TABLE_SIZE (1u << LOG2_T)
#define PRIME_Y    2654435761u
#define PRIME_Z    805459861u

#define NB        32768     // 32^3 buckets
#define HIST_B    1024      // histogram blocks (grid-stride, global atomics)
#define CVT_B     4096      // cvt blocks folded into hist launch
#define SCAT_B    2048      // scatter blocks

typedef float v4f __attribute__((ext_vector_type(4)));
typedef _Float16 v8h __attribute__((ext_vector_type(8)));

// ---------------- Morton key, 3x5 bits (bucketing only) ----------------
__device__ __forceinline__ uint32_t part1by2(uint32_t v) {
    v &= 0x3FFu;
    v = (v | (v << 16)) & 0x030000FFu;
    v = (v | (v <<  8)) & 0x0300F00Fu;
    v = (v | (v <<  4)) & 0x030C30C3u;
    v = (v | (v <<  2)) & 0x09249249u;
    return v;
}
__device__ __forceinline__ uint32_t morton_key(float xr, float yr, float zr) {
    int vx = (int)((xr * 0.5f + 0.5f) * 32.0f);
    int vy = (int)((yr * 0.5f + 0.5f) * 32.0f);
    int vz = (int)((zr * 0.5f + 0.5f) * 32.0f);
    vx = vx < 0 ? 0 : (vx > 31 ? 31 : vx);
    vy = vy < 0 ? 0 : (vy > 31 ? 31 : vy);
    vz = vz < 0 ? 0 : (vz > 31 ? 31 : vz);
    return part1by2((uint32_t)vx) | (part1by2((uint32_t)vy) << 1)
         | (part1by2((uint32_t)vz) << 2);   // 15-bit key
}

// ============== sort v2: global-atomic counting sort ======================
// Intra-bucket order is irrelevant (perm is applied consistently), so the
// LDS-histogram / per-block-offset machinery (64MB metadata + 2 scan
// kernels) collapses to: atomic hist -> one 32K scan -> atomic scatter.
// Blocks [0, HIST_B): grid-stride histogram via device atomicAdd.
// Blocks [HIST_B, HIST_B+CVT_B): table f32 -> packed-f16 conversion (folded
// in so its streaming overlaps the histogram).
__global__ __launch_bounds__(256)
void hist_cvt_kernel(const float* __restrict__ x, uint32_t* __restrict__ hist,
                     int n,
                     const float* __restrict__ tables,
                     uint32_t* __restrict__ tab16)
{
    if (blockIdx.x >= HIST_B) {
        // ---- cvt part: 4 entry-pairs per thread, coalesced ----
        // CVT_B * 256 * 4 pairs = 4M pairs = 8M entries = 16 * 2^19 total.
        const int cb = blockIdx.x - HIST_B;
        const size_t base_pair = (size_t)cb * 256 * 4;
        #pragma unroll
        for (int k = 0; k < 4; ++k) {
            const size_t e2 = base_pair + (size_t)k * 256 + threadIdx.x;
            const size_t base = e2 * 2;   // entry id
            const float4 v = *(const float4*)(tables + base * 2);
            union { _Float16 h[2]; uint32_t u; } p0, p1;
            p0.h[0] = (_Float16)v.x; p0.h[1] = (_Float16)v.y;
            p1.h[0] = (_Float16)v.z; p1.h[1] = (_Float16)v.w;
            *(uint2*)(tab16 + base) = make_uint2(p0.u, p1.u);
        }
        return;
    }
    const int stride = HIST_B * 256;
    for (int i = blockIdx.x * 256 + threadIdx.x; i < n; i += stride) {
        const uint32_t key = morton_key(x[3*i], x[3*i+1], x[3*i+2]);
        atomicAdd(&hist[key], 1u);
    }
}

// single-block exclusive scan of the 32K bucket counts -> base[]
__global__ __launch_bounds__(1024)
void scan32k_kernel(const uint32_t* __restrict__ cnt,
                    uint32_t* __restrict__ base)
{
    __shared__ uint32_t s[1024];
    const int t = threadIdx.x;
    uint32_t loc[32];
    uint32_t sum = 0;
    #pragma unroll
    for (int j = 0; j < 32; ++j) { loc[j] = cnt[t * 32 + j]; sum += loc[j]; }
    s[t] = sum; __syncthreads();
    #pragma unroll
    for (int d = 1; d < 1024; d <<= 1) {
        const uint32_t u = (t >= d) ? s[t - d] : 0;
        __syncthreads();
        s[t] += u;
        __syncthreads();
    }
    uint32_t run = s[t] - sum;   // exclusive prefix of this thread's chunk
    #pragma unroll
    for (int j = 0; j < 32; ++j) { base[t * 32 + j] = run; run += loc[j]; }
}

// scatter: pos = atomicAdd(&base[key], 1)  (base is consumed/destroyed).
// Writes xs4 (padded float4, ONE 16B store) + perm[pos]=i (sorted -> orig).
__global__ __launch_bounds__(256)
void scatter_kernel(const float* __restrict__ x,
                    uint32_t* __restrict__ base,
                    float4* __restrict__ xs4,      // [N] (w unused)
                    int* __restrict__ perm,        // [N] sorted pos -> orig idx
                    int n)
{
    const int stride = SCAT_B * 256;
    for (int i = blockIdx.x * 256 + threadIdx.x; i < n; i += stride) {
        const float a = x[3*i], c = x[3*i+1], d = x[3*i+2];
        const uint32_t key = morton_key(a, c, d);
        const uint32_t pos = atomicAdd(&base[key], 1u);
        xs4[pos]  = make_float4(a, c, d, 0.0f);
        perm[pos] = i;
    }
}

// ============================ encode (f16 tables) ============================
// Level-major 2D grid (blockIdx.y = level, slow-varying): each XCD's 4MB L2
// holds the current level's 2MB f16 table -> gathers are L2 hits.
// BRANCHLESS gather: the old (cx&1) even/odd split was per-lane divergent, so
// nearly every wave executed BOTH paths (12 VMEM issues + double address
// math). Now: for each yz-corner load the aligned entry-PAIR containing idx_a
// and the pair containing idx_b (2 x 8B loads, always), select the packed u32
// half. Even cx: both loads hit the same line (4 lines/point, unchanged);
// odd: 8 lines (unchanged). Line count identical, VMEM issues 12 -> 8,
// single-path VALU, zero divergence.
__device__ __forceinline__ float2 unpk16(uint32_t u) {
    union { uint32_t u; _Float16 h[2]; } c; c.u = u;
    return make_float2((float)c.h[0], (float)c.h[1]);
}

__global__ __launch_bounds__(256, 8)
void encode_f16_kernel(const float4* __restrict__ xs4,        // [N] sorted
                       const uint32_t* __restrict__ tab16,    // [16][T] 2xf16
                       const float* __restrict__ resolutions, // [16]
                       uint32_t* __restrict__ a_ws2,          // [16][N] 2xf16 x256
                       int n)
{
    const int l = blockIdx.y;
    int p = blockIdx.x * blockDim.x + threadIdx.x;
    if (p >= n) p = n - 1;

    const float4 xv = xs4[p];
    const float x0 = xv.x * 0.5f + 0.5f;
    const float x1 = xv.y * 0.5f + 0.5f;
    const float x2 = xv.z * 0.5f + 0.5f;

    const float res = resolutions[l];   // uniform -> scalar
    const float px = x0 * res, py = x1 * res, pz = x2 * res;
    const float fx = floorf(px), fy = floorf(py), fz = floorf(pz);
    const float wx = px - fx, wy = py - fy, wz = pz - fz;
    const uint32_t cx = (uint32_t)fx;
    const uint32_t cy = (uint32_t)fy;
    const uint32_t cz = (uint32_t)fz;

    const uint32_t hy0 = cy * PRIME_Y, hy1 = hy0 + PRIME_Y;
    const uint32_t hz0 = cz * PRIME_Z, hz1 = hz0 + PRIME_Z;

    const float wx0 = 1.0f - wx, wy0 = 1.0f - wy, wz0 = 1.0f - wz;

    const uint32_t* __restrict__ tab = tab16 + (size_t)l * (size_t)TABLE_SIZE;

    const uint32_t hyz[4] = { hy0 ^ hz0, hy1 ^ hz0, hy0 ^ hz1, hy1 ^ hz1 };

    float2 cva[4], cvb[4];

    #pragma unroll
    for (int q = 0; q < 4; ++q) {
        const uint32_t idx_a = (cx        ^ hyz[q]) & (TABLE_SIZE - 1u);
        const uint32_t idx_b = ((cx + 1u) ^ hyz[q]) & (TABLE_SIZE - 1u);
        const uint2 u2a = *(const uint2*)(tab + (idx_a & ~1u));
        const uint2 u2b = *(const uint2*)(tab + (idx_b & ~1u));
        const uint32_t wa = (idx_a & 1u) ? u2a.y : u2a.x;
        const uint32_t wb = (idx_b & 1u) ? u2b.y : u2b.x;
        cva[q] = unpk16(wa);
        cvb[q] = unpk16(wb);
    }

    float f0 = 0.0f, f1 = 0.0f;
    #pragma unroll
    for (int q = 0; q < 4; ++q) {
        const float yf = (q & 1) ? wy : wy0;
        const float zf = (q & 2) ? wz : wz0;
        const float wgt_a = (wx0 * yf) * zf;
        const float wgt_b = (wx  * yf) * zf;
        f0 = fmaf(wgt_a, cva[q].x, f0);
        f1 = fmaf(wgt_a, cva[q].y, f1);
        f0 = fmaf(wgt_b, cvb[q].x, f0);
        f1 = fmaf(wgt_b, cvb[q].y, f1);
    }

    union { _Float16 h[2]; uint32_t u; } pk;
    pk.h[0] = (_Float16)(f0 * 256.0f);
    pk.h[1] = (_Float16)(f1 * 256.0f);
    // nontemporal: a_ws2 is written once, read once -- keep it from evicting
    // table lines in L2.
    __builtin_nontemporal_store(pk.u, a_ws2 + (size_t)l * n + p);
}

// ---------- tier-B encode: f32 tables (fallback for small workspace) -----
__global__ __launch_bounds__(256, 8)
void encode_kernel(const float4* __restrict__ xs4,        // [N] sorted
                   const float* __restrict__ tables,      // [16, T, 2]
                   const float* __restrict__ resolutions, // [16]
                   uint32_t* __restrict__ a_ws2,          // [16][N] 2xf16 x256
                   int n)
{
    const int l = blockIdx.y;
    int p = blockIdx.x * blockDim.x + threadIdx.x;
    if (p >= n) p = n - 1;

    const float4 xv = xs4[p];
    const float x0 = xv.x * 0.5f + 0.5f;
    const float x1 = xv.y * 0.5f + 0.5f;
    const float x2 = xv.z * 0.5f + 0.5f;

    const float res = resolutions[l];
    const float px = x0 * res, py = x1 * res, pz = x2 * res;
    const float fx = floorf(px), fy = floorf(py), fz = floorf(pz);
    const float wx = px - fx, wy = py - fy, wz = pz - fz;
    const uint32_t cx = (uint32_t)fx;
    const uint32_t cy = (uint32_t)fy;
    const uint32_t cz = (uint32_t)fz;

    const uint32_t hy0 = cy * PRIME_Y, hy1 = hy0 + PRIME_Y;
    const uint32_t hz0 = cz * PRIME_Z, hz1 = hz0 + PRIME_Z;

    const float wx0 = 1.0f - wx, wy0 = 1.0f - wy, wz0 = 1.0f - wz;

    const float* __restrict__ tab = tables + (size_t)l * (size_t)TABLE_SIZE * 2u;

    const uint32_t hyz[4] = { hy0 ^ hz0, hy1 ^ hz0, hy0 ^ hz1, hy1 ^ hz1 };

    float f0 = 0.0f, f1 = 0.0f;
    #pragma unroll
    for (int q = 0; q < 4; ++q) {
        const uint32_t idx_a = (cx        ^ hyz[q]) & (TABLE_SIZE - 1u);
        const uint32_t idx_b = ((cx + 1u) ^ hyz[q]) & (TABLE_SIZE - 1u);
        const float2 fa = *(const float2*)(tab + 2u * idx_a);
        const float2 fb = *(const float2*)(tab + 2u * idx_b);
        const float yf = (q & 1) ? wy : wy0;
        const float zf = (q & 2) ? wz : wz0;
        const float wgt_a = (wx0 * yf) * zf;
        const float wgt_b = (wx  * yf) * zf;
        f0 = fmaf(wgt_a, fa.x, f0);
        f1 = fmaf(wgt_a, fa.y, f1);
        f0 = fmaf(wgt_b, fb.x, f0);
        f1 = fmaf(wgt_b, fb.y, f1);
    }

    union { _Float16 h[2]; uint32_t u; } pk;
    pk.h[0] = (_Float16)(f0 * 256.0f);
    pk.h[1] = (_Float16)(f1 * 256.0f);
    __builtin_nontemporal_store(pk.u, a_ws2 + (size_t)l * n + p);
}

// ============================ MFMA MLP ============================
// Loop-invariant per-lane scalars (256*b1, 256*b2, W3) live in LDS (shared
// with the activation buffer so LICM can't hoist them back into registers).
#define MLP_CB1 4096
#define MLP_CB2 4160
#define MLP_CW3 4224
__global__ __launch_bounds__(256, 2)
void mlp_mfma_kernel(const uint32_t* __restrict__ a_ws2, // [16][N] 2xf16 x256
                     const float* __restrict__ W1,
                     const float* __restrict__ b1,
                     const float* __restrict__ W2,
                     const float* __restrict__ b2,
                     const float* __restrict__ W3,
                     const float* __restrict__ b3,
                     const int* __restrict__ perm,       // sorted pos -> orig
                     float* __restrict__ out,            // [N] original order
                     int n)
{
    __shared__ float lds[4 * 64 * 16 + 192];

    const int lane    = threadIdx.x & 63;
    const int wave_id = threadIdx.x >> 6;
    const int m       = lane & 15;
    const int q       = lane >> 4;
    float* __restrict__ myl = &lds[wave_id * 1024];

    if (threadIdx.x < 64) {
        lds[MLP_CB1 + threadIdx.x] = 256.0f * b1[threadIdx.x];
        lds[MLP_CB2 + threadIdx.x] = 256.0f * b2[threadIdx.x];
        lds[MLP_CW3 + threadIdx.x] = W3[threadIdx.x];
    }

    const float b3s = b3[0];

    v8h a1[4];
    #pragma unroll
    for (int t = 0; t < 4; ++t)
        #pragma unroll
        for (int j = 0; j < 8; ++j)
            a1[t][j] = (_Float16)W1[(8 * q + j) * 64 + 16 * t + m];

    v8h a2[2][4];
    #pragma unroll
    for (int c = 0; c < 2; ++c)
        #pragma unroll
        for (int t = 0; t < 4; ++t)
            #pragma unroll
            for (int j = 0; j < 8; ++j)
                a2[c][t][j] = (_Float16)W2[(32 * c + 8 * q + j) * 64 + 16 * t + m];

    __syncthreads();   // cb1/cb2/cw3 ready

    const int nt = (n + 15) >> 4;
    const int stride = gridDim.x * 4;
    const int gw = blockIdx.x * 4 + wave_id;
    if (gw >= nt) return;

    union BF { uint32_t w[4]; v8h h; };

    v8h bh;
    {
        const int p0 = gw * 16;
        const int pr = (p0 + m < n) ? (p0 + m) : (n - 1);
        BF ub;
        #pragma unroll
        for (int lv = 0; lv < 4; ++lv)
            ub.w[lv] = __builtin_nontemporal_load(
                a_ws2 + (size_t)(4 * q + lv) * n + pr);
        bh = ub.h;
    }

    for (int tile = gw; tile < nt; tile += stride) {
        const int p0 = tile * 16;

        v8h bhn = bh;
        const int nx = tile + stride;
        if (nx < nt) {
            const int p0n = nx * 16;
            const int prn = (p0n + m < n) ? (p0n + m) : (n - 1);
            BF ub;
            #pragma unroll
            for (int lv = 0; lv < 4; ++lv)
                ub.w[lv] = __builtin_nontemporal_load(
                    a_ws2 + (size_t)(4 * q + lv) * n + prn);
            bhn = ub.h;
        }

        v4f acc1[4];
        #pragma unroll
        for (int t = 0; t < 4; ++t) {
            acc1[t] = *(const v4f*)&lds[MLP_CB1 + 16 * t + 4 * q]; // bcast read
            acc1[t] = __builtin_amdgcn_mfma_f32_16x16x32_f16(a1[t], bh, acc1[t], 0, 0, 0);
        }

        #pragma unroll
        for (int t = 0; t < 4; ++t)
            #pragma unroll
            for (int r = 0; r < 4; ++r)
                myl[(16 * t + 4 * q + r) * 16 + m] = fmaxf(acc1[t][r], 0.0f);
        __threadfence_block();

        v8h b2h[2];
        #pragma unroll
        for (int c = 0; c < 2; ++c)
            #pragma unroll
            for (int j = 0; j < 8; ++j)
                b2h[c][j] = (_Float16)myl[(32 * c + 8 * q + j) * 16 + m];

        v4f acc2[4];
        #pragma unroll
        for (int t = 0; t < 4; ++t) {
            acc2[t] = *(const v4f*)&lds[MLP_CB2 + 16 * t + 4 * q];
            acc2[t] = __builtin_amdgcn_mfma_f32_16x16x32_f16(a2[0][t], b2h[0], acc2[t], 0, 0, 0);
            acc2[t] = __builtin_amdgcn_mfma_f32_16x16x32_f16(a2[1][t], b2h[1], acc2[t], 0, 0, 0);
        }

        float partial = 0.0f;
        #pragma unroll
        for (int t = 0; t < 4; ++t) {
            const v4f w3q = *(const v4f*)&lds[MLP_CW3 + 16 * t + 4 * q];
            #pragma unroll
            for (int r = 0; r < 4; ++r)
                partial = fmaf(fmaxf(acc2[t][r], 0.0f), w3q[r], partial);
        }

        partial += __shfl_xor(partial, 16);
        partial += __shfl_xor(partial, 32);

        if (q == 0 && p0 + m < n)
            out[perm[p0 + m]] = partial * (1.0f / 256.0f) + b3s;

        bh = bhn;
    }
}

// ==================== Fallback: fused kernel ====================
__global__ __launch_bounds__(256, 4)
void hashgrid_mlp_fused(const float* __restrict__ x,
                        const float* __restrict__ tables,
                        const float* __restrict__ resolutions,
                        const float* __restrict__ W1,
                        const float* __restrict__ b1,
                        const float* __restrict__ W2,
                        const float* __restrict__ b2,
                        const float* __restrict__ W3,
                        const float* __restrict__ b3,
                        float* __restrict__ out,
                        int n)
{
    const int i  = blockIdx.x * blockDim.x + threadIdx.x;
    const int ip = (i < n) ? i : (n - 1);

    const float x0 = x[3 * ip + 0] * 0.5f + 0.5f;
    const float x1 = x[3 * ip + 1] * 0.5f + 0.5f;
    const float x2 = x[3 * ip + 2] * 0.5f + 0.5f;

    float h1[64];
    #pragma unroll
    for (int j = 0; j < 64; ++j) h1[j] = b1[j];

    #pragma unroll
    for (int l = 0; l < N_LEVELS; ++l) {
        const float res = resolutions[l];
        const float px = x0 * res, py = x1 * res, pz = x2 * res;
        const float fx = floorf(px), fy = floorf(py), fz = floorf(pz);
        const float wx = px - fx, wy = py - fy, wz = pz - fz;
        const uint32_t cx = (uint32_t)fx;
        const uint32_t cy = (uint32_t)fy;
        const uint32_t cz = (uint32_t)fz;
        const uint32_t hx0 = cx,           hx1 = cx + 1u;
        const uint32_t hy0 = cy * PRIME_Y, hy1 = hy0 + PRIME_Y;
        const uint32_t hz0 = cz * PRIME_Z, hz1 = hz0 + PRIME_Z;
        const float wx0 = 1.0f - wx, wy0 = 1.0f - wy, wz0 = 1.0f - wz;
        const float* __restrict__ tab = tables + (size_t)l * (size_t)TABLE_SIZE * 2u;

        float f0 = 0.0f, f1 = 0.0f;
        #pragma unroll
        for (int c = 0; c < 8; ++c) {
            const uint32_t h = ((c & 1) ? hx1 : hx0) ^
                               ((c & 2) ? hy1 : hy0) ^
                               ((c & 4) ? hz1 : hz0);
            const uint32_t idx = h & (TABLE_SIZE - 1u);
            const float2 fv = *(const float2*)(tab + 2u * idx);
            const float wgt = ((c & 1) ? wx : wx0) *
                              ((c & 2) ? wy : wy0) *
                              ((c & 4) ? wz : wz0);
            f0 = fmaf(wgt, fv.x, f0);
            f1 = fmaf(wgt, fv.y, f1);
        }
        const float* __restrict__ w1a = W1 + (2 * l + 0) * 64;
        const float* __restrict__ w1b = W1 + (2 * l + 1) * 64;
        #pragma unroll
        for (int j = 0; j < 64; ++j)
            h1[j] = fmaf(f1, w1b[j], fmaf(f0, w1a[j], h1[j]));
    }

    #pragma unroll
    for (int j = 0; j < 64; ++j) h1[j] = fmaxf(h1[j], 0.0f);

    float accum = b3[0];
    #pragma unroll
    for (int half = 0; half < 2; ++half) {
        float h2[32];
        #pragma unroll
        for (int j = 0; j < 32; ++j) h2[j] = b2[half * 32 + j];
        #pragma unroll
        for (int k = 0; k < 64; ++k) {
            const float hk = h1[k];
            const float* __restrict__ w2row = W2 + k * 64 + half * 32;
            #pragma unroll
            for (int j = 0; j < 32; ++j)
                h2[j] = fmaf(hk, w2row[j], h2[j]);
        }
        #pragma unroll
        for (int j = 0; j < 32; ++j)
            accum = fmaf(fmaxf(h2[j], 0.0f), W3[half * 32 + j], accum);
    }
    out[ip] = accum;
}

extern "C" void kernel_launch(void* const* d_in, const int* in_sizes, int n_in,
                              void* d_out, int out_size, void* d_ws, size_t ws_size,
                              hipStream_t stream) {
    const float* x           = (const float*)d_in[0];
    const float* tables      = (const float*)d_in[1];
    const float* resolutions = (const float*)d_in[2];
    const float* W1          = (const float*)d_in[3];
    const float* b1          = (const float*)d_in[4];
    const float* W2          = (const float*)d_in[5];
    const float* b2          = (const float*)d_in[6];
    const float* W3          = (const float*)d_in[7];
    const float* b3          = (const float*)d_in[8];
    float* out               = (float*)d_out;

    const int n = out_size;  // 2,000,000
    const int block = 256;
    const int grid_pts = (n + block - 1) / block;

    // ---- workspace layout ----
    size_t off = 0;
    #define CARVE(bytes) (off = (off + 255) & ~(size_t)255, off += (bytes), off - (bytes))
    const size_t aws_off   = CARVE((size_t)16 * n * sizeof(uint32_t)); // 128 MB
    const size_t xs_off    = CARVE((size_t)n * sizeof(float4));        //  32 MB
    const size_t perm_off  = CARVE((size_t)n * sizeof(int));           //   8 MB
    const size_t hist_off  = CARVE((size_t)NB * sizeof(uint32_t));     // 128 KB
    const size_t base_off  = CARVE((size_t)NB * sizeof(uint32_t));     // 128 KB
    const size_t total_ws_B = off;
    const size_t tab16_off = CARVE((size_t)N_LEVELS * TABLE_SIZE * sizeof(uint32_t)); // 32 MB
    const size_t total_ws_A = off;
    #undef CARVE

    if (ws_size >= total_ws_B) {
        const bool f16tab = (ws_size >= total_ws_A);
        char* ws = (char*)d_ws;
        uint32_t* a_ws2  = (uint32_t*)(ws + aws_off);
        float4*   xs4    = (float4*)(ws + xs_off);
        int*      perm   = (int*)(ws + perm_off);
        uint32_t* hist   = (uint32_t*)(ws + hist_off);
        uint32_t* base   = (uint32_t*)(ws + base_off);
        uint32_t* tab16  = (uint32_t*)(ws + tab16_off);

        hipMemsetAsync(hist, 0, (size_t)NB * sizeof(uint32_t), stream);

        // hist (+ folded table cvt when tier-A)
        const int hist_grid = HIST_B + (f16tab ? CVT_B : 0);
        hist_cvt_kernel<<<hist_grid, block, 0, stream>>>(
            x, hist, n, tables, f16tab ? tab16 : (uint32_t*)nullptr);
        scan32k_kernel<<<1, 1024, 0, stream>>>(hist, base);
        scatter_kernel<<<SCAT_B, block, 0, stream>>>(x, base, xs4, perm, n);

        dim3 grid_enc(grid_pts, N_LEVELS);   // y = level, slow-varying
        if (f16tab) {
            encode_f16_kernel<<<grid_enc, block, 0, stream>>>(
                xs4, tab16, resolutions, a_ws2, n);
        } else {
            encode_kernel<<<grid_enc, block, 0, stream>>>(
                xs4, tables, resolutions, a_ws2, n);
        }
        mlp_mfma_kernel<<<1024, block, 0, stream>>>(a_ws2, W1, b1, W2, b2, W3, b3,
                                                    perm, out, n);
    } else {
        hashgrid_mlp_fused<<<grid_pts, block, 0, stream>>>(
            x, tables, resolutions, W1, b1, W2, b2, W3, b3, out, n);
    }
}

// Round 9
// 575.232 us; speedup vs baseline: 1.2959x; 1.2959x over previous
//
#include <hip/hip_runtime.h>
#include <hip/hip_bf16.h>
#include <stdint.h>

#define N_LEVELS   16
#define LOG2_T     19
#define TABLE_SIZE (1u << LOG2_T)
#define PRIME_Y    2654435761u
#define PRIME_Z    805459861u

#define NB        32768     // 32^3 buckets
#define SORT_B    256       // sort blocks (each owns a contiguous point chunk)
#define SORT_T    512       // threads per sort block
#define CVT_B     2048      // extra blocks folded into hist launch for table cvt

typedef float v4f __attribute__((ext_vector_type(4)));
typedef _Float16 v8h __attribute__((ext_vector_type(8)));

// ---------------- Morton key, 3x5 bits (bucketing only) ----------------
__device__ __forceinline__ uint32_t part1by2(uint32_t v) {
    v &= 0x3FFu;
    v = (v | (v << 16)) & 0x030000FFu;
    v = (v | (v <<  8)) & 0x0300F00Fu;
    v = (v | (v <<  4)) & 0x030C30C3u;
    v = (v | (v <<  2)) & 0x09249249u;
    return v;
}
__device__ __forceinline__ uint32_t morton_key(float xr, float yr, float zr) {
    int vx = (int)((xr * 0.5f + 0.5f) * 32.0f);
    int vy = (int)((yr * 0.5f + 0.5f) * 32.0f);
    int vz = (int)((zr * 0.5f + 0.5f) * 32.0f);
    vx = vx < 0 ? 0 : (vx > 31 ? 31 : vx);
    vy = vy < 0 ? 0 : (vy > 31 ? 31 : vy);
    vz = vz < 0 ? 0 : (vz > 31 ? 31 : vz);
    return part1by2((uint32_t)vx) | (part1by2((uint32_t)vy) << 1)
         | (part1by2((uint32_t)vz) << 2);   // 15-bit key
}

// ============== sort, NO device atomics (LDS-histogram counting sort) =====
// (round-8 lesson: global-atomic hist/scatter cost +140us -- keep LDS ranks.)
// Blocks [0, SORT_B): per-chunk LDS histogram.
// Blocks [SORT_B, SORT_B+CVT_B): table f32 -> packed-f16 conversion (folded
// in so its streaming overlaps the histogram).
__global__ __launch_bounds__(SORT_T)
void hist_cvt_kernel(const float* __restrict__ x, uint32_t* __restrict__ g_hist,
                     int n, int chunk,
                     const float* __restrict__ tables,
                     uint32_t* __restrict__ tab16)
{
    __shared__ uint32_t pack[NB / 2];
    if (blockIdx.x >= SORT_B) {
        // ---- cvt part: 4 entry-pairs per thread, coalesced ----
        const int cb = blockIdx.x - SORT_B;
        const size_t base_pair = (size_t)cb * SORT_T * 4;
        #pragma unroll
        for (int k = 0; k < 4; ++k) {
            const size_t e2 = base_pair + (size_t)k * SORT_T + threadIdx.x;
            const size_t base = e2 * 2;   // entry id
            const float4 v = *(const float4*)(tables + base * 2);
            union { _Float16 h[2]; uint32_t u; } p0, p1;
            p0.h[0] = (_Float16)v.x; p0.h[1] = (_Float16)v.y;
            p1.h[0] = (_Float16)v.z; p1.h[1] = (_Float16)v.w;
            *(uint2*)(tab16 + base) = make_uint2(p0.u, p1.u);
        }
        return;
    }
    const int b = blockIdx.x, t = threadIdx.x;
    for (int w = t; w < NB / 2; w += SORT_T) pack[w] = 0;
    __syncthreads();
    const int beg = b * chunk;
    const int end = (beg + chunk < n) ? (beg + chunk) : n;
    for (int i = beg + t; i < end; i += SORT_T) {
        const uint32_t key = morton_key(x[3*i], x[3*i+1], x[3*i+2]);
        atomicAdd(&pack[key >> 1], 1u << ((key & 1u) << 4));
    }
    __syncthreads();
    uint32_t* __restrict__ dst = g_hist + (size_t)b * NB;
    for (int w = t; w < NB / 2; w += SORT_T) {
        const uint32_t p = pack[w];
        dst[2*w]     = p & 0xFFFFu;
        dst[2*w + 1] = p >> 16;
    }
}

// column scan: part[b][key] = sum_{b'<b} hist[b'][key]; totals[key] = full sum
__global__ __launch_bounds__(256)
void scan_cols_kernel(const uint32_t* __restrict__ g_hist,
                      uint32_t* __restrict__ g_part,
                      uint32_t* __restrict__ totals)
{
    const int key = blockIdx.x * 256 + threadIdx.x;   // 0..NB-1
    uint32_t run = 0;
    #pragma unroll 8
    for (int b = 0; b < SORT_B; ++b) {
        const size_t idx = (size_t)b * NB + key;
        const uint32_t v = g_hist[idx];
        g_part[idx] = run;
        run += v;
    }
    totals[key] = run;
}

__global__ void scan_block_kernel(const uint32_t* __restrict__ counts,
                                  uint32_t* __restrict__ prefix,
                                  uint32_t* __restrict__ blocksum) {
    __shared__ uint32_t s[256];
    const int t = threadIdx.x;
    const int i = blockIdx.x * 256 + t;
    const uint32_t v = counts[i];
    s[t] = v; __syncthreads();
    #pragma unroll
    for (int d = 1; d < 256; d <<= 1) {
        const uint32_t u = (t >= d) ? s[t - d] : 0;
        __syncthreads();
        s[t] += u;
        __syncthreads();
    }
    prefix[i] = s[t] - v;
    if (t == 255) blocksum[blockIdx.x] = s[255];
}

__global__ void scan_top_kernel(const uint32_t* __restrict__ blocksum,
                                uint32_t* __restrict__ blockbase, int nb) {
    __shared__ uint32_t s[1024];
    const int t = threadIdx.x;
    const uint32_t v = (t < nb) ? blocksum[t] : 0;
    s[t] = v; __syncthreads();
    #pragma unroll
    for (int d = 1; d < 1024; d <<= 1) {
        const uint32_t u = (t >= d) ? s[t - d] : 0;
        __syncthreads();
        s[t] += u;
        __syncthreads();
    }
    if (t < nb) blockbase[t] = s[t] - v;
}

// scatter: rank from LDS counters, pos = pref+bbase+part+rank.
// Writes xs4 (padded float4, ONE 16B store) + perm[pos]=i (sorted -> orig).
__global__ __launch_bounds__(SORT_T)
void scatter_kernel(const float* __restrict__ x,
                    const uint32_t* __restrict__ pref,
                    const uint32_t* __restrict__ bbase,
                    const uint32_t* __restrict__ g_part,
                    float4* __restrict__ xs4,      // [N] (w unused)
                    int* __restrict__ perm,        // [N] sorted pos -> orig idx
                    int n, int chunk)
{
    __shared__ uint32_t pack[NB / 2];
    const int b = blockIdx.x, t = threadIdx.x;
    for (int w = t; w < NB / 2; w += SORT_T) pack[w] = 0;
    __syncthreads();
    const uint32_t* __restrict__ part = g_part + (size_t)b * NB;
    const int beg = b * chunk;
    const int end = (beg + chunk < n) ? (beg + chunk) : n;
    for (int i = beg + t; i < end; i += SORT_T) {
        const float a = x[3*i], c = x[3*i+1], d = x[3*i+2];
        const uint32_t key = morton_key(a, c, d);
        const uint32_t sh = (key & 1u) << 4;
        uint32_t r = atomicAdd(&pack[key >> 1], 1u << sh);
        r = (r >> sh) & 0xFFFFu;
        const uint32_t pos = pref[key] + bbase[key >> 8] + part[key] + r;
        xs4[pos]  = make_float4(a, c, d, 0.0f);
        perm[pos] = i;
    }
}

// ============================ encode (f16 tables, 2 points/thread) ==========
// Level-major 2D grid (blockIdx.y = level): each XCD's 4MB L2 holds the
// current level's 2MB f16 table -> gathers are L2 hits.
// ILP experiment: counters show nothing saturated (VALU 39%, HBM 20%,
// occ at the 8-wave/EU cap) -> latency-bound, so each thread now gathers
// TWO points with the divergent branches restructured to contain LOADS ONLY
// (selection deferred to a branchless consume phase) -- both points' 8-16
// loads stay in flight together. Line count / FETCH unchanged.
// (round-8 lesson: always-pair branchless gather raised even-lane line
// requests and regressed; this keeps the 4-load even path.)
__device__ __forceinline__ float2 unpk16(uint32_t u) {
    union { uint32_t u; _Float16 h[2]; } c; c.u = u;
    return make_float2((float)c.h[0], (float)c.h[1]);
}

__global__ __launch_bounds__(256)
void encode_f16_kernel(const float4* __restrict__ xs4,        // [N] sorted
                       const uint32_t* __restrict__ tab16,    // [16][T] 2xf16
                       const float* __restrict__ resolutions, // [16]
                       uint32_t* __restrict__ a_ws2,          // [16][N] 2xf16 x256
                       int n, int half)
{
    const int l = blockIdx.y;
    int p0 = blockIdx.x * blockDim.x + threadIdx.x;
    if (p0 >= half) p0 = half - 1;          // tail: duplicate work, same value
    int p1 = p0 + half;
    if (p1 >= n) p1 = n - 1;

    const float res = resolutions[l];   // uniform -> scalar
    const uint32_t* __restrict__ tab = tab16 + (size_t)l * (size_t)TABLE_SIZE;
    const int pp[2] = { p0, p1 };

    uint2    wreg[2][4];
    uint32_t swp[2];                    // bit q: swap pair halves
    float    wxa[2], wya[2], wza[2];

    #pragma unroll
    for (int s = 0; s < 2; ++s) {
        const float4 xv = xs4[pp[s]];
        const float x0 = xv.x * 0.5f + 0.5f;
        const float x1 = xv.y * 0.5f + 0.5f;
        const float x2 = xv.z * 0.5f + 0.5f;

        const float px = x0 * res, py = x1 * res, pz = x2 * res;
        const float fx = floorf(px), fy = floorf(py), fz = floorf(pz);
        wxa[s] = px - fx; wya[s] = py - fy; wza[s] = pz - fz;
        const uint32_t cx = (uint32_t)fx;
        const uint32_t cy = (uint32_t)fy;
        const uint32_t cz = (uint32_t)fz;

        const uint32_t hy0 = cy * PRIME_Y, hy1 = hy0 + PRIME_Y;
        const uint32_t hz0 = cz * PRIME_Z, hz1 = hz0 + PRIME_Z;
        const uint32_t hyz[4] = { hy0 ^ hz0, hy1 ^ hz0, hy0 ^ hz1, hy1 ^ hz1 };

        uint32_t sm = 0;
        if ((cx & 1u) == 0u) {
            // even cx: idx_b == idx_a^1 -> one aligned 8B pair load per corner
            #pragma unroll
            for (int q = 0; q < 4; ++q) {
                const uint32_t idx_a = (cx ^ hyz[q]) & (TABLE_SIZE - 1u);
                wreg[s][q] = *(const uint2*)(tab + (idx_a & ~1u));
                sm |= (idx_a & 1u) << q;
            }
        } else {
            #pragma unroll
            for (int q = 0; q < 4; ++q) {
                const uint32_t idx_a = (cx        ^ hyz[q]) & (TABLE_SIZE - 1u);
                const uint32_t idx_b = ((cx + 1u) ^ hyz[q]) & (TABLE_SIZE - 1u);
                wreg[s][q].x = tab[idx_a];
                wreg[s][q].y = tab[idx_b];
            }
        }
        swp[s] = sm;
    }

    // branchless consume (first use of wreg waits on the outstanding loads)
    #pragma unroll
    for (int s = 0; s < 2; ++s) {
        const float wx = wxa[s], wy = wya[s], wz = wza[s];
        const float wx0 = 1.0f - wx, wy0 = 1.0f - wy, wz0 = 1.0f - wz;
        float f0 = 0.0f, f1 = 0.0f;
        #pragma unroll
        for (int q = 0; q < 4; ++q) {
            const bool sw = (swp[s] >> q) & 1u;
            const uint32_t wa = sw ? wreg[s][q].y : wreg[s][q].x;
            const uint32_t wb = sw ? wreg[s][q].x : wreg[s][q].y;
            const float2 ca = unpk16(wa);
            const float2 cb = unpk16(wb);
            const float yf = (q & 1) ? wy : wy0;
            const float zf = (q & 2) ? wz : wz0;
            const float wgt_a = (wx0 * yf) * zf;
            const float wgt_b = (wx  * yf) * zf;
            f0 = fmaf(wgt_a, ca.x, f0);
            f1 = fmaf(wgt_a, ca.y, f1);
            f0 = fmaf(wgt_b, cb.x, f0);
            f1 = fmaf(wgt_b, cb.y, f1);
        }
        union { _Float16 h[2]; uint32_t u; } pk;
        pk.h[0] = (_Float16)(f0 * 256.0f);
        pk.h[1] = (_Float16)(f1 * 256.0f);
        __builtin_nontemporal_store(pk.u, a_ws2 + (size_t)l * n + pp[s]);
    }
}

// ---------- tier-B encode: f32 tables (fallback for small workspace) -----
__global__ __launch_bounds__(256, 8)
void encode_kernel(const float4* __restrict__ xs4,        // [N] sorted
                   const float* __restrict__ tables,      // [16, T, 2]
                   const float* __restrict__ resolutions, // [16]
                   uint32_t* __restrict__ a_ws2,          // [16][N] 2xf16 x256
                   int n)
{
    const int l = blockIdx.y;
    int p = blockIdx.x * blockDim.x + threadIdx.x;
    if (p >= n) p = n - 1;

    const float4 xv = xs4[p];
    const float x0 = xv.x * 0.5f + 0.5f;
    const float x1 = xv.y * 0.5f + 0.5f;
    const float x2 = xv.z * 0.5f + 0.5f;

    const float res = resolutions[l];
    const float px = x0 * res, py = x1 * res, pz = x2 * res;
    const float fx = floorf(px), fy = floorf(py), fz = floorf(pz);
    const float wx = px - fx, wy = py - fy, wz = pz - fz;
    const uint32_t cx = (uint32_t)fx;
    const uint32_t cy = (uint32_t)fy;
    const uint32_t cz = (uint32_t)fz;

    const uint32_t hy0 = cy * PRIME_Y, hy1 = hy0 + PRIME_Y;
    const uint32_t hz0 = cz * PRIME_Z, hz1 = hz0 + PRIME_Z;

    const float wx0 = 1.0f - wx, wy0 = 1.0f - wy, wz0 = 1.0f - wz;

    const float* __restrict__ tab = tables + (size_t)l * (size_t)TABLE_SIZE * 2u;

    const uint32_t hyz[4] = { hy0 ^ hz0, hy1 ^ hz0, hy0 ^ hz1, hy1 ^ hz1 };

    float2 cva[4], cvb[4];

    if ((cx & 1u) == 0u) {
        #pragma unroll
        for (int q = 0; q < 4; ++q) {
            const uint32_t idx_a = (cx ^ hyz[q]) & (TABLE_SIZE - 1u);
            const uint32_t base  = idx_a & ~1u;
            const float4 f4 = *(const float4*)(tab + 2u * base);
            const bool hi = (idx_a & 1u) != 0u;
            cva[q] = hi ? make_float2(f4.z, f4.w) : make_float2(f4.x, f4.y);
            cvb[q] = hi ? make_float2(f4.x, f4.y) : make_float2(f4.z, f4.w);
        }
    } else {
        const uint32_t hx0 = cx, hx1 = cx + 1u;
        #pragma unroll
        for (int q = 0; q < 4; ++q) {
            const uint32_t idx_a = (hx0 ^ hyz[q]) & (TABLE_SIZE - 1u);
            const uint32_t idx_b = (hx1 ^ hyz[q]) & (TABLE_SIZE - 1u);
            cva[q] = *(const float2*)(tab + 2u * idx_a);
            cvb[q] = *(const float2*)(tab + 2u * idx_b);
        }
    }

    float f0 = 0.0f, f1 = 0.0f;
    #pragma unroll
    for (int q = 0; q < 4; ++q) {
        const float yf = (q & 1) ? wy : wy0;
        const float zf = (q & 2) ? wz : wz0;
        const float wgt_a = (wx0 * yf) * zf;
        const float wgt_b = (wx  * yf) * zf;
        f0 = fmaf(wgt_a, cva[q].x, f0);
        f1 = fmaf(wgt_a, cva[q].y, f1);
        f0 = fmaf(wgt_b, cvb[q].x, f0);
        f1 = fmaf(wgt_b, cvb[q].y, f1);
    }

    union { _Float16 h[2]; uint32_t u; } pk;
    pk.h[0] = (_Float16)(f0 * 256.0f);
    pk.h[1] = (_Float16)(f1 * 256.0f);
    __builtin_nontemporal_store(pk.u, a_ws2 + (size_t)l * n + p);
}

// ============================ MFMA MLP ============================
// Loop-invariant per-lane scalars (256*b1, 256*b2, W3) live in LDS (shared
// with the activation buffer so LICM can't hoist them back into registers).
#define MLP_CB1 4096
#define MLP_CB2 4160
#define MLP_CW3 4224
__global__ __launch_bounds__(256, 2)
void mlp_mfma_kernel(const uint32_t* __restrict__ a_ws2, // [16][N] 2xf16 x256
                     const float* __restrict__ W1,
                     const float* __restrict__ b1,
                     const float* __restrict__ W2,
                     const float* __restrict__ b2,
                     const float* __restrict__ W3,
                     const float* __restrict__ b3,
                     const int* __restrict__ perm,       // sorted pos -> orig
                     float* __restrict__ out,            // [N] original order
                     int n)
{
    __shared__ float lds[4 * 64 * 16 + 192];

    const int lane    = threadIdx.x & 63;
    const int wave_id = threadIdx.x >> 6;
    const int m       = lane & 15;
    const int q       = lane >> 4;
    float* __restrict__ myl = &lds[wave_id * 1024];

    if (threadIdx.x < 64) {
        lds[MLP_CB1 + threadIdx.x] = 256.0f * b1[threadIdx.x];
        lds[MLP_CB2 + threadIdx.x] = 256.0f * b2[threadIdx.x];
        lds[MLP_CW3 + threadIdx.x] = W3[threadIdx.x];
    }

    const float b3s = b3[0];

    v8h a1[4];
    #pragma unroll
    for (int t = 0; t < 4; ++t)
        #pragma unroll
        for (int j = 0; j < 8; ++j)
            a1[t][j] = (_Float16)W1[(8 * q + j) * 64 + 16 * t + m];

    v8h a2[2][4];
    #pragma unroll
    for (int c = 0; c < 2; ++c)
        #pragma unroll
        for (int t = 0; t < 4; ++t)
            #pragma unroll
            for (int j = 0; j < 8; ++j)
                a2[c][t][j] = (_Float16)W2[(32 * c + 8 * q + j) * 64 + 16 * t + m];

    __syncthreads();   // cb1/cb2/cw3 ready

    const int nt = (n + 15) >> 4;
    const int stride = gridDim.x * 4;
    const int gw = blockIdx.x * 4 + wave_id;
    if (gw >= nt) return;

    union BF { uint32_t w[4]; v8h h; };

    v8h bh;
    {
        const int p0 = gw * 16;
        const int pr = (p0 + m < n) ? (p0 + m) : (n - 1);
        BF ub;
        #pragma unroll
        for (int lv = 0; lv < 4; ++lv)
            ub.w[lv] = __builtin_nontemporal_load(
                a_ws2 + (size_t)(4 * q + lv) * n + pr);
        bh = ub.h;
    }

    for (int tile = gw; tile < nt; tile += stride) {
        const int p0 = tile * 16;

        v8h bhn = bh;
        const int nx = tile + stride;
        if (nx < nt) {
            const int p0n = nx * 16;
            const int prn = (p0n + m < n) ? (p0n + m) : (n - 1);
            BF ub;
            #pragma unroll
            for (int lv = 0; lv < 4; ++lv)
                ub.w[lv] = __builtin_nontemporal_load(
                    a_ws2 + (size_t)(4 * q + lv) * n + prn);
            bhn = ub.h;
        }

        v4f acc1[4];
        #pragma unroll
        for (int t = 0; t < 4; ++t) {
            acc1[t] = *(const v4f*)&lds[MLP_CB1 + 16 * t + 4 * q]; // bcast read
            acc1[t] = __builtin_amdgcn_mfma_f32_16x16x32_f16(a1[t], bh, acc1[t], 0, 0, 0);
        }

        #pragma unroll
        for (int t = 0; t < 4; ++t)
            #pragma unroll
            for (int r = 0; r < 4; ++r)
                myl[(16 * t + 4 * q + r) * 16 + m] = fmaxf(acc1[t][r], 0.0f);
        __threadfence_block();

        v8h b2h[2];
        #pragma unroll
        for (int c = 0; c < 2; ++c)
            #pragma unroll
            for (int j = 0; j < 8; ++j)
                b2h[c][j] = (_Float16)myl[(32 * c + 8 * q + j) * 16 + m];

        v4f acc2[4];
        #pragma unroll
        for (int t = 0; t < 4; ++t) {
            acc2[t] = *(const v4f*)&lds[MLP_CB2 + 16 * t + 4 * q];
            acc2[t] = __builtin_amdgcn_mfma_f32_16x16x32_f16(a2[0][t], b2h[0], acc2[t], 0, 0, 0);
            acc2[t] = __builtin_amdgcn_mfma_f32_16x16x32_f16(a2[1][t], b2h[1], acc2[t], 0, 0, 0);
        }

        float partial = 0.0f;
        #pragma unroll
        for (int t = 0; t < 4; ++t) {
            const v4f w3q = *(const v4f*)&lds[MLP_CW3 + 16 * t + 4 * q];
            #pragma unroll
            for (int r = 0; r < 4; ++r)
                partial = fmaf(fmaxf(acc2[t][r], 0.0f), w3q[r], partial);
        }

        partial += __shfl_xor(partial, 16);
        partial += __shfl_xor(partial, 32);

        if (q == 0 && p0 + m < n)
            out[perm[p0 + m]] = partial * (1.0f / 256.0f) + b3s;

        bh = bhn;
    }
}

// ==================== Fallback: fused kernel ====================
__global__ __launch_bounds__(256, 4)
void hashgrid_mlp_fused(const float* __restrict__ x,
                        const float* __restrict__ tables,
                        const float* __restrict__ resolutions,
                        const float* __restrict__ W1,
                        const float* __restrict__ b1,
                        const float* __restrict__ W2,
                        const float* __restrict__ b2,
                        const float* __restrict__ W3,
                        const float* __restrict__ b3,
                        float* __restrict__ out,
                        int n)
{
    const int i  = blockIdx.x * blockDim.x + threadIdx.x;
    const int ip = (i < n) ? i : (n - 1);

    const float x0 = x[3 * ip + 0] * 0.5f + 0.5f;
    const float x1 = x[3 * ip + 1] * 0.5f + 0.5f;
    const float x2 = x[3 * ip + 2] * 0.5f + 0.5f;

    float h1[64];
    #pragma unroll
    for (int j = 0; j < 64; ++j) h1[j] = b1[j];

    #pragma unroll
    for (int l = 0; l < N_LEVELS; ++l) {
        const float res = resolutions[l];
        const float px = x0 * res, py = x1 * res, pz = x2 * res;
        const float fx = floorf(px), fy = floorf(py), fz = floorf(pz);
        const float wx = px - fx, wy = py - fy, wz = pz - fz;
        const uint32_t cx = (uint32_t)fx;
        const uint32_t cy = (uint32_t)fy;
        const uint32_t cz = (uint32_t)fz;
        const uint32_t hx0 = cx,           hx1 = cx + 1u;
        const uint32_t hy0 = cy * PRIME_Y, hy1 = hy0 + PRIME_Y;
        const uint32_t hz0 = cz * PRIME_Z, hz1 = hz0 + PRIME_Z;
        const float wx0 = 1.0f - wx, wy0 = 1.0f - wy, wz0 = 1.0f - wz;
        const float* __restrict__ tab = tables + (size_t)l * (size_t)TABLE_SIZE * 2u;

        float f0 = 0.0f, f1 = 0.0f;
        #pragma unroll
        for (int c = 0; c < 8; ++c) {
            const uint32_t h = ((c & 1) ? hx1 : hx0) ^
                               ((c & 2) ? hy1 : hy0) ^
                               ((c & 4) ? hz1 : hz0);
            const uint32_t idx = h & (TABLE_SIZE - 1u);
            const float2 fv = *(const float2*)(tab + 2u * idx);
            const float wgt = ((c & 1) ? wx : wx0) *
                              ((c & 2) ? wy : wy0) *
                              ((c & 4) ? wz : wz0);
            f0 = fmaf(wgt, fv.x, f0);
            f1 = fmaf(wgt, fv.y, f1);
        }
        const float* __restrict__ w1a = W1 + (2 * l + 0) * 64;
        const float* __restrict__ w1b = W1 + (2 * l + 1) * 64;
        #pragma unroll
        for (int j = 0; j < 64; ++j)
            h1[j] = fmaf(f1, w1b[j], fmaf(f0, w1a[j], h1[j]));
    }

    #pragma unroll
    for (int j = 0; j < 64; ++j) h1[j] = fmaxf(h1[j], 0.0f);

    float accum = b3[0];
    #pragma unroll
    for (int half = 0; half < 2; ++half) {
        float h2[32];
        #pragma unroll
        for (int j = 0; j < 32; ++j) h2[j] = b2[half * 32 + j];
        #pragma unroll
        for (int k = 0; k < 64; ++k) {
            const float hk = h1[k];
            const float* __restrict__ w2row = W2 + k * 64 + half * 32;
            #pragma unroll
            for (int j = 0; j < 32; ++j)
                h2[j] = fmaf(hk, w2row[j], h2[j]);
        }
        #pragma unroll
        for (int j = 0; j < 32; ++j)
            accum = fmaf(fmaxf(h2[j], 0.0f), W3[half * 32 + j], accum);
    }
    out[ip] = accum;
}

extern "C" void kernel_launch(void* const* d_in, const int* in_sizes, int n_in,
                              void* d_out, int out_size, void* d_ws, size_t ws_size,
                              hipStream_t stream) {
    const float* x           = (const float*)d_in[0];
    const float* tables      = (const float*)d_in[1];
    const float* resolutions = (const float*)d_in[2];
    const float* W1          = (const float*)d_in[3];
    const float* b1          = (const float*)d_in[4];
    const float* W2          = (const float*)d_in[5];
    const float* b2          = (const float*)d_in[6];
    const float* W3          = (const float*)d_in[7];
    const float* b3          = (const float*)d_in[8];
    float* out               = (float*)d_out;

    const int n = out_size;  // 2,000,000
    const int block = 256;
    const int grid_pts = (n + block - 1) / block;
    const int chunk = (n + SORT_B - 1) / SORT_B;
    const int half = (n + 1) / 2;
    const int grid_half = (half + block - 1) / block;

    // ---- workspace layout ----
    // a_ws2 (128 MB) is written only by encode, AFTER the sort finishes, so
    // the sort's metadata (g_hist 32 MB + g_part 32 MB) aliases into it.
    // tab16 (32 MB) sits at the end so tier B (no-f16-table) still fits
    // smaller workspaces.
    size_t off = 0;
    #define CARVE(bytes) (off = (off + 255) & ~(size_t)255, off += (bytes), off - (bytes))
    const size_t aws_off   = CARVE((size_t)16 * n * sizeof(uint32_t)); // 128 MB
    const size_t xs_off    = CARVE((size_t)n * sizeof(float4));        //  32 MB
    const size_t perm_off  = CARVE((size_t)n * sizeof(int));           //   8 MB
    const size_t tot_off   = CARVE((size_t)NB * sizeof(uint32_t));
    const size_t pref_off  = CARVE((size_t)NB * sizeof(uint32_t));
    const size_t bsum_off  = CARVE(1024 * sizeof(uint32_t));
    const size_t bbase_off = CARVE(1024 * sizeof(uint32_t));
    const size_t total_ws_B = off;
    const size_t tab16_off = CARVE((size_t)N_LEVELS * TABLE_SIZE * sizeof(uint32_t)); // 32 MB
    const size_t total_ws_A = off;
    #undef CARVE

    if (ws_size >= total_ws_B) {
        const bool f16tab = (ws_size >= total_ws_A);
        char* ws = (char*)d_ws;
        uint32_t* a_ws2  = (uint32_t*)(ws + aws_off);
        uint32_t* g_hist = (uint32_t*)(ws + aws_off);                          // alias
        uint32_t* g_part = (uint32_t*)(ws + aws_off + (size_t)SORT_B * NB * 4);// alias
        float4*   xs4    = (float4*)(ws + xs_off);
        int*      perm   = (int*)(ws + perm_off);
        uint32_t* totals = (uint32_t*)(ws + tot_off);
        uint32_t* pref   = (uint32_t*)(ws + pref_off);
        uint32_t* bsum   = (uint32_t*)(ws + bsum_off);
        uint32_t* bbase  = (uint32_t*)(ws + bbase_off);
        uint32_t* tab16  = (uint32_t*)(ws + tab16_off);

        // hist (+ folded table cvt when tier-A)
        const int hist_grid = SORT_B + (f16tab ? CVT_B : 0);
        hist_cvt_kernel<<<hist_grid, SORT_T, 0, stream>>>(
            x, g_hist, n, chunk, tables, f16tab ? tab16 : (uint32_t*)nullptr);
        scan_cols_kernel<<<NB / 256, block, 0, stream>>>(g_hist, g_part, totals);
        scan_block_kernel<<<NB / 256, block, 0, stream>>>(totals, pref, bsum);
        scan_top_kernel<<<1, 1024, 0, stream>>>(bsum, bbase, NB / 256);
        scatter_kernel<<<SORT_B, SORT_T, 0, stream>>>(
            x, pref, bbase, g_part, xs4, perm, n, chunk);

        if (f16tab) {
            dim3 grid_enc(grid_half, N_LEVELS);   // 2 points per thread
            encode_f16_kernel<<<grid_enc, block, 0, stream>>>(
                xs4, tab16, resolutions, a_ws2, n, half);
        } else {
            dim3 grid_enc(grid_pts, N_LEVELS);
            encode_kernel<<<grid_enc, block, 0, stream>>>(
                xs4, tables, resolutions, a_ws2, n);
        }
        mlp_mfma_kernel<<<1024, block, 0, stream>>>(a_ws2, W1, b1, W2, b2, W3, b3,
                                                    perm, out, n);
    } else {
        hashgrid_mlp_fused<<<grid_pts, block, 0, stream>>>(
            x, tables, resolutions, W1, b1, W2, b2, W3, b3, out, n);
    }
}

// Round 10
// 550.069 us; speedup vs baseline: 1.3552x; 1.0457x over previous
//
#include <hip/hip_runtime.h>
#include <hip/hip_bf16.h>
#include <stdint.h>

#define N_LEVELS   16
#define LOG2_T     19
#define TABLE_SIZE (1u << LOG2_T)
#define PRIME_Y    2654435761u
#define PRIME_Z    805459861u

#define NB        32768     // 32^3 buckets
#define SORT_B    256       // sort blocks (each owns a contiguous point chunk)
#define SORT_T    512       // threads per sort block
#define CVT_B     2048      // extra blocks folded into hist launch for table cvt

typedef float v4f __attribute__((ext_vector_type(4)));
typedef _Float16 v8h __attribute__((ext_vector_type(8)));

// ---------------- Morton key, 3x5 bits (bucketing only) ----------------
__device__ __forceinline__ uint32_t part1by2(uint32_t v) {
    v &= 0x3FFu;
    v = (v | (v << 16)) & 0x030000FFu;
    v = (v | (v <<  8)) & 0x0300F00Fu;
    v = (v | (v <<  4)) & 0x030C30C3u;
    v = (v | (v <<  2)) & 0x09249249u;
    return v;
}
__device__ __forceinline__ uint32_t morton_key(float xr, float yr, float zr) {
    int vx = (int)((xr * 0.5f + 0.5f) * 32.0f);
    int vy = (int)((yr * 0.5f + 0.5f) * 32.0f);
    int vz = (int)((zr * 0.5f + 0.5f) * 32.0f);
    vx = vx < 0 ? 0 : (vx > 31 ? 31 : vx);
    vy = vy < 0 ? 0 : (vy > 31 ? 31 : vy);
    vz = vz < 0 ? 0 : (vz > 31 ? 31 : vz);
    return part1by2((uint32_t)vx) | (part1by2((uint32_t)vy) << 1)
         | (part1by2((uint32_t)vz) << 2);   // 15-bit key
}

// ============== sort, NO device atomics (LDS-histogram counting sort) =====
// (round-8 lesson: global-atomic hist/scatter cost +140us -- keep LDS ranks.)
// Blocks [0, SORT_B): per-chunk LDS histogram.
// Blocks [SORT_B, SORT_B+CVT_B): table f32 -> packed-f16 conversion (folded
// in so its streaming overlaps the histogram).
__global__ __launch_bounds__(SORT_T)
void hist_cvt_kernel(const float* __restrict__ x, uint32_t* __restrict__ g_hist,
                     int n, int chunk,
                     const float* __restrict__ tables,
                     uint32_t* __restrict__ tab16)
{
    __shared__ uint32_t pack[NB / 2];
    if (blockIdx.x >= SORT_B) {
        // ---- cvt part: 4 entry-pairs per thread, coalesced ----
        const int cb = blockIdx.x - SORT_B;
        const size_t base_pair = (size_t)cb * SORT_T * 4;
        #pragma unroll
        for (int k = 0; k < 4; ++k) {
            const size_t e2 = base_pair + (size_t)k * SORT_T + threadIdx.x;
            const size_t base = e2 * 2;   // entry id
            const float4 v = *(const float4*)(tables + base * 2);
            union { _Float16 h[2]; uint32_t u; } p0, p1;
            p0.h[0] = (_Float16)v.x; p0.h[1] = (_Float16)v.y;
            p1.h[0] = (_Float16)v.z; p1.h[1] = (_Float16)v.w;
            *(uint2*)(tab16 + base) = make_uint2(p0.u, p1.u);
        }
        return;
    }
    const int b = blockIdx.x, t = threadIdx.x;
    for (int w = t; w < NB / 2; w += SORT_T) pack[w] = 0;
    __syncthreads();
    const int beg = b * chunk;
    const int end = (beg + chunk < n) ? (beg + chunk) : n;
    for (int i = beg + t; i < end; i += SORT_T) {
        const uint32_t key = morton_key(x[3*i], x[3*i+1], x[3*i+2]);
        atomicAdd(&pack[key >> 1], 1u << ((key & 1u) << 4));
    }
    __syncthreads();
    uint32_t* __restrict__ dst = g_hist + (size_t)b * NB;
    for (int w = t; w < NB / 2; w += SORT_T) {
        const uint32_t p = pack[w];
        dst[2*w]     = p & 0xFFFFu;
        dst[2*w + 1] = p >> 16;
    }
}

// column scan: part[b][key] = sum_{b'<b} hist[b'][key]; totals[key] = full sum
__global__ __launch_bounds__(256)
void scan_cols_kernel(const uint32_t* __restrict__ g_hist,
                      uint32_t* __restrict__ g_part,
                      uint32_t* __restrict__ totals)
{
    const int key = blockIdx.x * 256 + threadIdx.x;   // 0..NB-1
    uint32_t run = 0;
    #pragma unroll 8
    for (int b = 0; b < SORT_B; ++b) {
        const size_t idx = (size_t)b * NB + key;
        const uint32_t v = g_hist[idx];
        g_part[idx] = run;
        run += v;
    }
    totals[key] = run;
}

// single-block exclusive scan of the 32K bucket totals -> base[]
// (replaces scan_block + scan_top + addback: proven in round 8)
__global__ __launch_bounds__(1024)
void scan32k_kernel(const uint32_t* __restrict__ cnt,
                    uint32_t* __restrict__ base)
{
    __shared__ uint32_t s[1024];
    const int t = threadIdx.x;
    uint32_t loc[32];
    uint32_t sum = 0;
    #pragma unroll
    for (int j = 0; j < 32; ++j) { loc[j] = cnt[t * 32 + j]; sum += loc[j]; }
    s[t] = sum; __syncthreads();
    #pragma unroll
    for (int d = 1; d < 1024; d <<= 1) {
        const uint32_t u = (t >= d) ? s[t - d] : 0;
        __syncthreads();
        s[t] += u;
        __syncthreads();
    }
    uint32_t run = s[t] - sum;   // exclusive prefix of this thread's chunk
    #pragma unroll
    for (int j = 0; j < 32; ++j) { base[t * 32 + j] = run; run += loc[j]; }
}

// scatter: rank from LDS counters, pos = base+part+rank.
// Writes xs4 (padded float4, ONE 16B store) + rank_inv[i]=pos (COALESCED by
// original index -- the inverse permutation for the gather-unscatter).
__global__ __launch_bounds__(SORT_T)
void scatter_kernel(const float* __restrict__ x,
                    const uint32_t* __restrict__ base,
                    const uint32_t* __restrict__ g_part,
                    float4* __restrict__ xs4,      // [N] (w unused)
                    int* __restrict__ rank_inv,    // [N] orig idx -> sorted pos
                    int n, int chunk)
{
    __shared__ uint32_t pack[NB / 2];
    const int b = blockIdx.x, t = threadIdx.x;
    for (int w = t; w < NB / 2; w += SORT_T) pack[w] = 0;
    __syncthreads();
    const uint32_t* __restrict__ part = g_part + (size_t)b * NB;
    const int beg = b * chunk;
    const int end = (beg + chunk < n) ? (beg + chunk) : n;
    for (int i = beg + t; i < end; i += SORT_T) {
        const float a = x[3*i], c = x[3*i+1], d = x[3*i+2];
        const uint32_t key = morton_key(a, c, d);
        const uint32_t sh = (key & 1u) << 4;
        uint32_t r = atomicAdd(&pack[key >> 1], 1u << sh);
        r = (r >> sh) & 0xFFFFu;
        const uint32_t pos = base[key] + part[key] + r;
        xs4[pos]    = make_float4(a, c, d, 0.0f);
        rank_inv[i] = (int)pos;
    }
}

// ============================ encode (f16 tables, 2 points/thread) ==========
// Level-major 2D grid (blockIdx.y = level): each XCD's 4MB L2 holds the
// current level's 2MB f16 table -> gathers are L2 hits. 2-pt ILP (round 9,
// +3%); further ILP parked -- signature says per-CU MSHR/L2-latency cap.
__device__ __forceinline__ float2 unpk16(uint32_t u) {
    union { uint32_t u; _Float16 h[2]; } c; c.u = u;
    return make_float2((float)c.h[0], (float)c.h[1]);
}

__global__ __launch_bounds__(256)
void encode_f16_kernel(const float4* __restrict__ xs4,        // [N] sorted
                       const uint32_t* __restrict__ tab16,    // [16][T] 2xf16
                       const float* __restrict__ resolutions, // [16]
                       uint32_t* __restrict__ a_ws2,          // [16][N] 2xf16 x256
                       int n, int half)
{
    const int l = blockIdx.y;
    int p0 = blockIdx.x * blockDim.x + threadIdx.x;
    if (p0 >= half) p0 = half - 1;          // tail: duplicate work, same value
    int p1 = p0 + half;
    if (p1 >= n) p1 = n - 1;

    const float res = resolutions[l];   // uniform -> scalar
    const uint32_t* __restrict__ tab = tab16 + (size_t)l * (size_t)TABLE_SIZE;
    const int pp[2] = { p0, p1 };

    uint2    wreg[2][4];
    uint32_t swp[2];                    // bit q: swap pair halves
    float    wxa[2], wya[2], wza[2];

    #pragma unroll
    for (int s = 0; s < 2; ++s) {
        const float4 xv = xs4[pp[s]];
        const float x0 = xv.x * 0.5f + 0.5f;
        const float x1 = xv.y * 0.5f + 0.5f;
        const float x2 = xv.z * 0.5f + 0.5f;

        const float px = x0 * res, py = x1 * res, pz = x2 * res;
        const float fx = floorf(px), fy = floorf(py), fz = floorf(pz);
        wxa[s] = px - fx; wya[s] = py - fy; wza[s] = pz - fz;
        const uint32_t cx = (uint32_t)fx;
        const uint32_t cy = (uint32_t)fy;
        const uint32_t cz = (uint32_t)fz;

        const uint32_t hy0 = cy * PRIME_Y, hy1 = hy0 + PRIME_Y;
        const uint32_t hz0 = cz * PRIME_Z, hz1 = hz0 + PRIME_Z;
        const uint32_t hyz[4] = { hy0 ^ hz0, hy1 ^ hz0, hy0 ^ hz1, hy1 ^ hz1 };

        uint32_t sm = 0;
        if ((cx & 1u) == 0u) {
            // even cx: idx_b == idx_a^1 -> one aligned 8B pair load per corner
            #pragma unroll
            for (int q = 0; q < 4; ++q) {
                const uint32_t idx_a = (cx ^ hyz[q]) & (TABLE_SIZE - 1u);
                wreg[s][q] = *(const uint2*)(tab + (idx_a & ~1u));
                sm |= (idx_a & 1u) << q;
            }
        } else {
            #pragma unroll
            for (int q = 0; q < 4; ++q) {
                const uint32_t idx_a = (cx        ^ hyz[q]) & (TABLE_SIZE - 1u);
                const uint32_t idx_b = ((cx + 1u) ^ hyz[q]) & (TABLE_SIZE - 1u);
                wreg[s][q].x = tab[idx_a];
                wreg[s][q].y = tab[idx_b];
            }
        }
        swp[s] = sm;
    }

    // branchless consume (first use of wreg waits on the outstanding loads)
    #pragma unroll
    for (int s = 0; s < 2; ++s) {
        const float wx = wxa[s], wy = wya[s], wz = wza[s];
        const float wx0 = 1.0f - wx, wy0 = 1.0f - wy, wz0 = 1.0f - wz;
        float f0 = 0.0f, f1 = 0.0f;
        #pragma unroll
        for (int q = 0; q < 4; ++q) {
            const bool sw = (swp[s] >> q) & 1u;
            const uint32_t wa = sw ? wreg[s][q].y : wreg[s][q].x;
            const uint32_t wb = sw ? wreg[s][q].x : wreg[s][q].y;
            const float2 ca = unpk16(wa);
            const float2 cb = unpk16(wb);
            const float yf = (q & 1) ? wy : wy0;
            const float zf = (q & 2) ? wz : wz0;
            const float wgt_a = (wx0 * yf) * zf;
            const float wgt_b = (wx  * yf) * zf;
            f0 = fmaf(wgt_a, ca.x, f0);
            f1 = fmaf(wgt_a, ca.y, f1);
            f0 = fmaf(wgt_b, cb.x, f0);
            f1 = fmaf(wgt_b, cb.y, f1);
        }
        union { _Float16 h[2]; uint32_t u; } pk;
        pk.h[0] = (_Float16)(f0 * 256.0f);
        pk.h[1] = (_Float16)(f1 * 256.0f);
        __builtin_nontemporal_store(pk.u, a_ws2 + (size_t)l * n + pp[s]);
    }
}

// ---------- tier-B encode: f32 tables (fallback for small workspace) -----
__global__ __launch_bounds__(256, 8)
void encode_kernel(const float4* __restrict__ xs4,        // [N] sorted
                   const float* __restrict__ tables,      // [16, T, 2]
                   const float* __restrict__ resolutions, // [16]
                   uint32_t* __restrict__ a_ws2,          // [16][N] 2xf16 x256
                   int n)
{
    const int l = blockIdx.y;
    int p = blockIdx.x * blockDim.x + threadIdx.x;
    if (p >= n) p = n - 1;

    const float4 xv = xs4[p];
    const float x0 = xv.x * 0.5f + 0.5f;
    const float x1 = xv.y * 0.5f + 0.5f;
    const float x2 = xv.z * 0.5f + 0.5f;

    const float res = resolutions[l];
    const float px = x0 * res, py = x1 * res, pz = x2 * res;
    const float fx = floorf(px), fy = floorf(py), fz = floorf(pz);
    const float wx = px - fx, wy = py - fy, wz = pz - fz;
    const uint32_t cx = (uint32_t)fx;
    const uint32_t cy = (uint32_t)fy;
    const uint32_t cz = (uint32_t)fz;

    const uint32_t hy0 = cy * PRIME_Y, hy1 = hy0 + PRIME_Y;
    const uint32_t hz0 = cz * PRIME_Z, hz1 = hz0 + PRIME_Z;

    const float wx0 = 1.0f - wx, wy0 = 1.0f - wy, wz0 = 1.0f - wz;

    const float* __restrict__ tab = tables + (size_t)l * (size_t)TABLE_SIZE * 2u;

    const uint32_t hyz[4] = { hy0 ^ hz0, hy1 ^ hz0, hy0 ^ hz1, hy1 ^ hz1 };

    float2 cva[4], cvb[4];

    if ((cx & 1u) == 0u) {
        #pragma unroll
        for (int q = 0; q < 4; ++q) {
            const uint32_t idx_a = (cx ^ hyz[q]) & (TABLE_SIZE - 1u);
            const uint32_t base  = idx_a & ~1u;
            const float4 f4 = *(const float4*)(tab + 2u * base);
            const bool hi = (idx_a & 1u) != 0u;
            cva[q] = hi ? make_float2(f4.z, f4.w) : make_float2(f4.x, f4.y);
            cvb[q] = hi ? make_float2(f4.x, f4.y) : make_float2(f4.z, f4.w);
        }
    } else {
        const uint32_t hx0 = cx, hx1 = cx + 1u;
        #pragma unroll
        for (int q = 0; q < 4; ++q) {
            const uint32_t idx_a = (hx0 ^ hyz[q]) & (TABLE_SIZE - 1u);
            const uint32_t idx_b = (hx1 ^ hyz[q]) & (TABLE_SIZE - 1u);
            cva[q] = *(const float2*)(tab + 2u * idx_a);
            cvb[q] = *(const float2*)(tab + 2u * idx_b);
        }
    }

    float f0 = 0.0f, f1 = 0.0f;
    #pragma unroll
    for (int q = 0; q < 4; ++q) {
        const float yf = (q & 1) ? wy : wy0;
        const float zf = (q & 2) ? wz : wz0;
        const float wgt_a = (wx0 * yf) * zf;
        const float wgt_b = (wx  * yf) * zf;
        f0 = fmaf(wgt_a, cva[q].x, f0);
        f1 = fmaf(wgt_a, cva[q].y, f1);
        f0 = fmaf(wgt_b, cvb[q].x, f0);
        f1 = fmaf(wgt_b, cvb[q].y, f1);
    }

    union { _Float16 h[2]; uint32_t u; } pk;
    pk.h[0] = (_Float16)(f0 * 256.0f);
    pk.h[1] = (_Float16)(f1 * 256.0f);
    __builtin_nontemporal_store(pk.u, a_ws2 + (size_t)l * n + p);
}

// ============================ MFMA MLP ============================
// Writes outs[] COALESCED in sorted order. The previous out[perm[...]]
// scattered 4B stores made every 64B line of out partially-written by ~16
// random waves chip-wide -> write-allocate + cross-XCD line bouncing.
// Gather-form unscatter (below) replaces it.
// Loop-invariant per-lane scalars (256*b1, 256*b2, W3) live in LDS (shared
// with the activation buffer so LICM can't hoist them back into registers).
#define MLP_CB1 4096
#define MLP_CB2 4160
#define MLP_CW3 4224
__global__ __launch_bounds__(256, 2)
void mlp_mfma_kernel(const uint32_t* __restrict__ a_ws2, // [16][N] 2xf16 x256
                     const float* __restrict__ W1,
                     const float* __restrict__ b1,
                     const float* __restrict__ W2,
                     const float* __restrict__ b2,
                     const float* __restrict__ W3,
                     const float* __restrict__ b3,
                     float* __restrict__ outs,           // [N] sorted order
                     int n)
{
    __shared__ float lds[4 * 64 * 16 + 192];

    const int lane    = threadIdx.x & 63;
    const int wave_id = threadIdx.x >> 6;
    const int m       = lane & 15;
    const int q       = lane >> 4;
    float* __restrict__ myl = &lds[wave_id * 1024];

    if (threadIdx.x < 64) {
        lds[MLP_CB1 + threadIdx.x] = 256.0f * b1[threadIdx.x];
        lds[MLP_CB2 + threadIdx.x] = 256.0f * b2[threadIdx.x];
        lds[MLP_CW3 + threadIdx.x] = W3[threadIdx.x];
    }

    const float b3s = b3[0];

    v8h a1[4];
    #pragma unroll
    for (int t = 0; t < 4; ++t)
        #pragma unroll
        for (int j = 0; j < 8; ++j)
            a1[t][j] = (_Float16)W1[(8 * q + j) * 64 + 16 * t + m];

    v8h a2[2][4];
    #pragma unroll
    for (int c = 0; c < 2; ++c)
        #pragma unroll
        for (int t = 0; t < 4; ++t)
            #pragma unroll
            for (int j = 0; j < 8; ++j)
                a2[c][t][j] = (_Float16)W2[(32 * c + 8 * q + j) * 64 + 16 * t + m];

    __syncthreads();   // cb1/cb2/cw3 ready

    const int nt = (n + 15) >> 4;
    const int stride = gridDim.x * 4;
    const int gw = blockIdx.x * 4 + wave_id;
    if (gw >= nt) return;

    union BF { uint32_t w[4]; v8h h; };

    v8h bh;
    {
        const int p0 = gw * 16;
        const int pr = (p0 + m < n) ? (p0 + m) : (n - 1);
        BF ub;
        #pragma unroll
        for (int lv = 0; lv < 4; ++lv)
            ub.w[lv] = __builtin_nontemporal_load(
                a_ws2 + (size_t)(4 * q + lv) * n + pr);
        bh = ub.h;
    }

    for (int tile = gw; tile < nt; tile += stride) {
        const int p0 = tile * 16;

        v8h bhn = bh;
        const int nx = tile + stride;
        if (nx < nt) {
            const int p0n = nx * 16;
            const int prn = (p0n + m < n) ? (p0n + m) : (n - 1);
            BF ub;
            #pragma unroll
            for (int lv = 0; lv < 4; ++lv)
                ub.w[lv] = __builtin_nontemporal_load(
                    a_ws2 + (size_t)(4 * q + lv) * n + prn);
            bhn = ub.h;
        }

        v4f acc1[4];
        #pragma unroll
        for (int t = 0; t < 4; ++t) {
            acc1[t] = *(const v4f*)&lds[MLP_CB1 + 16 * t + 4 * q]; // bcast read
            acc1[t] = __builtin_amdgcn_mfma_f32_16x16x32_f16(a1[t], bh, acc1[t], 0, 0, 0);
        }

        #pragma unroll
        for (int t = 0; t < 4; ++t)
            #pragma unroll
            for (int r = 0; r < 4; ++r)
                myl[(16 * t + 4 * q + r) * 16 + m] = fmaxf(acc1[t][r], 0.0f);
        __threadfence_block();

        v8h b2h[2];
        #pragma unroll
        for (int c = 0; c < 2; ++c)
            #pragma unroll
            for (int j = 0; j < 8; ++j)
                b2h[c][j] = (_Float16)myl[(32 * c + 8 * q + j) * 16 + m];

        v4f acc2[4];
        #pragma unroll
        for (int t = 0; t < 4; ++t) {
            acc2[t] = *(const v4f*)&lds[MLP_CB2 + 16 * t + 4 * q];
            acc2[t] = __builtin_amdgcn_mfma_f32_16x16x32_f16(a2[0][t], b2h[0], acc2[t], 0, 0, 0);
            acc2[t] = __builtin_amdgcn_mfma_f32_16x16x32_f16(a2[1][t], b2h[1], acc2[t], 0, 0, 0);
        }

        float partial = 0.0f;
        #pragma unroll
        for (int t = 0; t < 4; ++t) {
            const v4f w3q = *(const v4f*)&lds[MLP_CW3 + 16 * t + 4 * q];
            #pragma unroll
            for (int r = 0; r < 4; ++r)
                partial = fmaf(fmaxf(acc2[t][r], 0.0f), w3q[r], partial);
        }

        partial += __shfl_xor(partial, 16);
        partial += __shfl_xor(partial, 32);

        if (q == 0 && p0 + m < n)
            outs[p0 + m] = partial * (1.0f / 256.0f) + b3s;

        bh = bhn;
    }
}

// out[i] = outs[rank_inv[i]] : coalesced read of rank_inv, coalesced write of
// out, random 4B gather from the 8MB outs (read-only -> replicates in L2s).
__global__ __launch_bounds__(256)
void unscatter_kernel(const float* __restrict__ outs,
                      const int* __restrict__ rank_inv,
                      float* __restrict__ out, int n) {
    const int i = blockIdx.x * blockDim.x + threadIdx.x;
    if (i < n) out[i] = outs[rank_inv[i]];
}

// ==================== Fallback: fused kernel ====================
__global__ __launch_bounds__(256, 4)
void hashgrid_mlp_fused(const float* __restrict__ x,
                        const float* __restrict__ tables,
                        const float* __restrict__ resolutions,
                        const float* __restrict__ W1,
                        const float* __restrict__ b1,
                        const float* __restrict__ W2,
                        const float* __restrict__ b2,
                        const float* __restrict__ W3,
                        const float* __restrict__ b3,
                        float* __restrict__ out,
                        int n)
{
    const int i  = blockIdx.x * blockDim.x + threadIdx.x;
    const int ip = (i < n) ? i : (n - 1);

    const float x0 = x[3 * ip + 0] * 0.5f + 0.5f;
    const float x1 = x[3 * ip + 1] * 0.5f + 0.5f;
    const float x2 = x[3 * ip + 2] * 0.5f + 0.5f;

    float h1[64];
    #pragma unroll
    for (int j = 0; j < 64; ++j) h1[j] = b1[j];

    #pragma unroll
    for (int l = 0; l < N_LEVELS; ++l) {
        const float res = resolutions[l];
        const float px = x0 * res, py = x1 * res, pz = x2 * res;
        const float fx = floorf(px), fy = floorf(py), fz = floorf(pz);
        const float wx = px - fx, wy = py - fy, wz = pz - fz;
        const uint32_t cx = (uint32_t)fx;
        const uint32_t cy = (uint32_t)fy;
        const uint32_t cz = (uint32_t)fz;
        const uint32_t hx0 = cx,           hx1 = cx + 1u;
        const uint32_t hy0 = cy * PRIME_Y, hy1 = hy0 + PRIME_Y;
        const uint32_t hz0 = cz * PRIME_Z, hz1 = hz0 + PRIME_Z;
        const float wx0 = 1.0f - wx, wy0 = 1.0f - wy, wz0 = 1.0f - wz;
        const float* __restrict__ tab = tables + (size_t)l * (size_t)TABLE_SIZE * 2u;

        float f0 = 0.0f, f1 = 0.0f;
        #pragma unroll
        for (int c = 0; c < 8; ++c) {
            const uint32_t h = ((c & 1) ? hx1 : hx0) ^
                               ((c & 2) ? hy1 : hy0) ^
                               ((c & 4) ? hz1 : hz0);
            const uint32_t idx = h & (TABLE_SIZE - 1u);
            const float2 fv = *(const float2*)(tab + 2u * idx);
            const float wgt = ((c & 1) ? wx : wx0) *
                              ((c & 2) ? wy : wy0) *
                              ((c & 4) ? wz : wz0);
            f0 = fmaf(wgt, fv.x, f0);
            f1 = fmaf(wgt, fv.y, f1);
        }
        const float* __restrict__ w1a = W1 + (2 * l + 0) * 64;
        const float* __restrict__ w1b = W1 + (2 * l + 1) * 64;
        #pragma unroll
        for (int j = 0; j < 64; ++j)
            h1[j] = fmaf(f1, w1b[j], fmaf(f0, w1a[j], h1[j]));
    }

    #pragma unroll
    for (int j = 0; j < 64; ++j) h1[j] = fmaxf(h1[j], 0.0f);

    float accum = b3[0];
    #pragma unroll
    for (int half = 0; half < 2; ++half) {
        float h2[32];
        #pragma unroll
        for (int j = 0; j < 32; ++j) h2[j] = b2[half * 32 + j];
        #pragma unroll
        for (int k = 0; k < 64; ++k) {
            const float hk = h1[k];
            const float* __restrict__ w2row = W2 + k * 64 + half * 32;
            #pragma unroll
            for (int j = 0; j < 32; ++j)
                h2[j] = fmaf(hk, w2row[j], h2[j]);
        }
        #pragma unroll
        for (int j = 0; j < 32; ++j)
            accum = fmaf(fmaxf(h2[j], 0.0f), W3[half * 32 + j], accum);
    }
    out[ip] = accum;
}

extern "C" void kernel_launch(void* const* d_in, const int* in_sizes, int n_in,
                              void* d_out, int out_size, void* d_ws, size_t ws_size,
                              hipStream_t stream) {
    const float* x           = (const float*)d_in[0];
    const float* tables      = (const float*)d_in[1];
    const float* resolutions = (const float*)d_in[2];
    const float* W1          = (const float*)d_in[3];
    const float* b1          = (const float*)d_in[4];
    const float* W2          = (const float*)d_in[5];
    const float* b2          = (const float*)d_in[6];
    const float* W3          = (const float*)d_in[7];
    const float* b3          = (const float*)d_in[8];
    float* out               = (float*)d_out;

    const int n = out_size;  // 2,000,000
    const int block = 256;
    const int grid_pts = (n + block - 1) / block;
    const int chunk = (n + SORT_B - 1) / SORT_B;
    const int half = (n + 1) / 2;
    const int grid_half = (half + block - 1) / block;

    // ---- workspace layout ----
    // a_ws2 (128 MB) is written only by encode, AFTER the sort finishes, so
    // the sort's metadata (g_hist 32 MB + g_part 32 MB) aliases into it.
    // tab16 (32 MB) sits at the end so tier B (no-f16-table) still fits
    // smaller workspaces.
    size_t off = 0;
    #define CARVE(bytes) (off = (off + 255) & ~(size_t)255, off += (bytes), off - (bytes))
    const size_t aws_off   = CARVE((size_t)16 * n * sizeof(uint32_t)); // 128 MB
    const size_t xs_off    = CARVE((size_t)n * sizeof(float4));        //  32 MB
    const size_t rank_off  = CARVE((size_t)n * sizeof(int));           //   8 MB
    const size_t outs_off  = CARVE((size_t)n * sizeof(float));         //   8 MB
    const size_t tot_off   = CARVE((size_t)NB * sizeof(uint32_t));
    const size_t base_off  = CARVE((size_t)NB * sizeof(uint32_t));
    const size_t total_ws_B = off;
    const size_t tab16_off = CARVE((size_t)N_LEVELS * TABLE_SIZE * sizeof(uint32_t)); // 32 MB
    const size_t total_ws_A = off;
    #undef CARVE

    if (ws_size >= total_ws_B) {
        const bool f16tab = (ws_size >= total_ws_A);
        char* ws = (char*)d_ws;
        uint32_t* a_ws2  = (uint32_t*)(ws + aws_off);
        uint32_t* g_hist = (uint32_t*)(ws + aws_off);                          // alias
        uint32_t* g_part = (uint32_t*)(ws + aws_off + (size_t)SORT_B * NB * 4);// alias
        float4*   xs4    = (float4*)(ws + xs_off);
        int*      rank   = (int*)(ws + rank_off);
        float*    outs   = (float*)(ws + outs_off);
        uint32_t* totals = (uint32_t*)(ws + tot_off);
        uint32_t* base   = (uint32_t*)(ws + base_off);
        uint32_t* tab16  = (uint32_t*)(ws + tab16_off);

        // hist (+ folded table cvt when tier-A)
        const int hist_grid = SORT_B + (f16tab ? CVT_B : 0);
        hist_cvt_kernel<<<hist_grid, SORT_T, 0, stream>>>(
            x, g_hist, n, chunk, tables, f16tab ? tab16 : (uint32_t*)nullptr);
        scan_cols_kernel<<<NB / 256, block, 0, stream>>>(g_hist, g_part, totals);
        scan32k_kernel<<<1, 1024, 0, stream>>>(totals, base);
        scatter_kernel<<<SORT_B, SORT_T, 0, stream>>>(
            x, base, g_part, xs4, rank, n, chunk);

        if (f16tab) {
            dim3 grid_enc(grid_half, N_LEVELS);   // 2 points per thread
            encode_f16_kernel<<<grid_enc, block, 0, stream>>>(
                xs4, tab16, resolutions, a_ws2, n, half);
        } else {
            dim3 grid_enc(grid_pts, N_LEVELS);
            encode_kernel<<<grid_enc, block, 0, stream>>>(
                xs4, tables, resolutions, a_ws2, n);
        }
        mlp_mfma_kernel<<<1024, block, 0, stream>>>(a_ws2, W1, b1, W2, b2, W3, b3,
                                                    outs, n);
        unscatter_kernel<<<grid_pts, block, 0, stream>>>(outs, rank, out, n);
    } else {
        hashgrid_mlp_fused<<<grid_pts, block, 0, stream>>>(
            x, tables, resolutions, W1, b1, W2, b2, W3, b3, out, n);
    }
}

// Round 11
// 540.544 us; speedup vs baseline: 1.3791x; 1.0176x over previous
//
#include <hip/hip_runtime.h>
#include <hip/hip_bf16.h>
#include <stdint.h>

#define N_LEVELS   16
#define LOG2_T     19
#define TABLE_SIZE (1u << LOG2_T)
#define PRIME_Y    2654435761u
#define PRIME_Z    805459861u

#define NB        32768     // 32^3 buckets
#define SORT_B    256       // sort blocks (each owns a contiguous point chunk)
#define SORT_T    512       // threads per sort block
#define CVT_B     2048      // extra blocks folded into hist launch for table cvt

typedef float v4f __attribute__((ext_vector_type(4)));
typedef _Float16 v8h __attribute__((ext_vector_type(8)));

// ---------------- Morton key, 3x5 bits (bucketing only) ----------------
__device__ __forceinline__ uint32_t part1by2(uint32_t v) {
    v &= 0x3FFu;
    v = (v | (v << 16)) & 0x030000FFu;
    v = (v | (v <<  8)) & 0x0300F00Fu;
    v = (v | (v <<  4)) & 0x030C30C3u;
    v = (v | (v <<  2)) & 0x09249249u;
    return v;
}
__device__ __forceinline__ uint32_t morton_key(float xr, float yr, float zr) {
    int vx = (int)((xr * 0.5f + 0.5f) * 32.0f);
    int vy = (int)((yr * 0.5f + 0.5f) * 32.0f);
    int vz = (int)((zr * 0.5f + 0.5f) * 32.0f);
    vx = vx < 0 ? 0 : (vx > 31 ? 31 : vx);
    vy = vy < 0 ? 0 : (vy > 31 ? 31 : vy);
    vz = vz < 0 ? 0 : (vz > 31 ? 31 : vz);
    return part1by2((uint32_t)vx) | (part1by2((uint32_t)vy) << 1)
         | (part1by2((uint32_t)vz) << 2);   // 15-bit key
}

// ============== sort, NO device atomics (LDS-histogram counting sort) =====
// (round-8 lesson: global-atomic hist/scatter cost +140us -- keep LDS ranks.)
// Blocks [0, SORT_B): per-chunk LDS histogram.
// Blocks [SORT_B, SORT_B+CVT_B): table f32 -> packed-f16 conversion (folded
// in so its streaming overlaps the histogram).
__global__ __launch_bounds__(SORT_T)
void hist_cvt_kernel(const float* __restrict__ x, uint32_t* __restrict__ g_hist,
                     int n, int chunk,
                     const float* __restrict__ tables,
                     uint32_t* __restrict__ tab16)
{
    __shared__ uint32_t pack[NB / 2];
    if (blockIdx.x >= SORT_B) {
        // ---- cvt part: 4 entry-pairs per thread, coalesced ----
        const int cb = blockIdx.x - SORT_B;
        const size_t base_pair = (size_t)cb * SORT_T * 4;
        #pragma unroll
        for (int k = 0; k < 4; ++k) {
            const size_t e2 = base_pair + (size_t)k * SORT_T + threadIdx.x;
            const size_t base = e2 * 2;   // entry id
            const float4 v = *(const float4*)(tables + base * 2);
            union { _Float16 h[2]; uint32_t u; } p0, p1;
            p0.h[0] = (_Float16)v.x; p0.h[1] = (_Float16)v.y;
            p1.h[0] = (_Float16)v.z; p1.h[1] = (_Float16)v.w;
            *(uint2*)(tab16 + base) = make_uint2(p0.u, p1.u);
        }
        return;
    }
    const int b = blockIdx.x, t = threadIdx.x;
    for (int w = t; w < NB / 2; w += SORT_T) pack[w] = 0;
    __syncthreads();
    const int beg = b * chunk;
    const int end = (beg + chunk < n) ? (beg + chunk) : n;
    for (int i = beg + t; i < end; i += SORT_T) {
        const uint32_t key = morton_key(x[3*i], x[3*i+1], x[3*i+2]);
        atomicAdd(&pack[key >> 1], 1u << ((key & 1u) << 4));
    }
    __syncthreads();
    uint32_t* __restrict__ dst = g_hist + (size_t)b * NB;
    for (int w = t; w < NB / 2; w += SORT_T) {
        const uint32_t p = pack[w];
        dst[2*w]     = p & 0xFFFFu;
        dst[2*w + 1] = p >> 16;
    }
}

// column scan: part[b][key] = sum_{b'<b} hist[b'][key]; totals[key] = full sum
__global__ __launch_bounds__(256)
void scan_cols_kernel(const uint32_t* __restrict__ g_hist,
                      uint32_t* __restrict__ g_part,
                      uint32_t* __restrict__ totals)
{
    const int key = blockIdx.x * 256 + threadIdx.x;   // 0..NB-1
    uint32_t run = 0;
    #pragma unroll 8
    for (int b = 0; b < SORT_B; ++b) {
        const size_t idx = (size_t)b * NB + key;
        const uint32_t v = g_hist[idx];
        g_part[idx] = run;
        run += v;
    }
    totals[key] = run;
}

// single-block exclusive scan of the 32K bucket totals -> base[]
__global__ __launch_bounds__(1024)
void scan32k_kernel(const uint32_t* __restrict__ cnt,
                    uint32_t* __restrict__ base)
{
    __shared__ uint32_t s[1024];
    const int t = threadIdx.x;
    uint32_t loc[32];
    uint32_t sum = 0;
    #pragma unroll
    for (int j = 0; j < 32; ++j) { loc[j] = cnt[t * 32 + j]; sum += loc[j]; }
    s[t] = sum; __syncthreads();
    #pragma unroll
    for (int d = 1; d < 1024; d <<= 1) {
        const uint32_t u = (t >= d) ? s[t - d] : 0;
        __syncthreads();
        s[t] += u;
        __syncthreads();
    }
    uint32_t run = s[t] - sum;   // exclusive prefix of this thread's chunk
    #pragma unroll
    for (int j = 0; j < 32; ++j) { base[t * 32 + j] = run; run += loc[j]; }
}

// scatter: rank from LDS counters, pos = base+part+rank.
// Writes xs4 (padded float4, ONE 16B store) + rank_inv[i]=pos (COALESCED by
// original index -- the inverse permutation for the gather-unscatter).
__global__ __launch_bounds__(SORT_T)
void scatter_kernel(const float* __restrict__ x,
                    const uint32_t* __restrict__ base,
                    const uint32_t* __restrict__ g_part,
                    float4* __restrict__ xs4,      // [N] (w unused)
                    int* __restrict__ rank_inv,    // [N] orig idx -> sorted pos
                    int n, int chunk)
{
    __shared__ uint32_t pack[NB / 2];
    const int b = blockIdx.x, t = threadIdx.x;
    for (int w = t; w < NB / 2; w += SORT_T) pack[w] = 0;
    __syncthreads();
    const uint32_t* __restrict__ part = g_part + (size_t)b * NB;
    const int beg = b * chunk;
    const int end = (beg + chunk < n) ? (beg + chunk) : n;
    for (int i = beg + t; i < end; i += SORT_T) {
        const float a = x[3*i], c = x[3*i+1], d = x[3*i+2];
        const uint32_t key = morton_key(a, c, d);
        const uint32_t sh = (key & 1u) << 4;
        uint32_t r = atomicAdd(&pack[key >> 1], 1u << sh);
        r = (r >> sh) & 0xFFFFu;
        const uint32_t pos = base[key] + part[key] + r;
        xs4[pos]    = make_float4(a, c, d, 0.0f);
        rank_inv[i] = (int)pos;
    }
}

// ============================ encode (f16 tables, 2 points/thread) ==========
// Level-major 2D grid (blockIdx.y = level): each XCD's 4MB L2 holds the
// current level's 2MB f16 table -> gathers are L2 hits. 2-pt ILP (round 9).
// PARKED at ~277us: TA address-lookup model (2M pts x 16 lvl x ~6 lookups /
// 256 CU / 2.4GHz ~ 290us at 1 lookup/cyc) says this is the structural floor.
__device__ __forceinline__ float2 unpk16(uint32_t u) {
    union { uint32_t u; _Float16 h[2]; } c; c.u = u;
    return make_float2((float)c.h[0], (float)c.h[1]);
}

__global__ __launch_bounds__(256)
void encode_f16_kernel(const float4* __restrict__ xs4,        // [N] sorted
                       const uint32_t* __restrict__ tab16,    // [16][T] 2xf16
                       const float* __restrict__ resolutions, // [16]
                       uint32_t* __restrict__ a_ws2,          // [16][N] 2xf16 x256
                       int n, int half)
{
    const int l = blockIdx.y;
    int p0 = blockIdx.x * blockDim.x + threadIdx.x;
    if (p0 >= half) p0 = half - 1;          // tail: duplicate work, same value
    int p1 = p0 + half;
    if (p1 >= n) p1 = n - 1;

    const float res = resolutions[l];   // uniform -> scalar
    const uint32_t* __restrict__ tab = tab16 + (size_t)l * (size_t)TABLE_SIZE;
    const int pp[2] = { p0, p1 };

    uint2    wreg[2][4];
    uint32_t swp[2];                    // bit q: swap pair halves
    float    wxa[2], wya[2], wza[2];

    #pragma unroll
    for (int s = 0; s < 2; ++s) {
        const float4 xv = xs4[pp[s]];
        const float x0 = xv.x * 0.5f + 0.5f;
        const float x1 = xv.y * 0.5f + 0.5f;
        const float x2 = xv.z * 0.5f + 0.5f;

        const float px = x0 * res, py = x1 * res, pz = x2 * res;
        const float fx = floorf(px), fy = floorf(py), fz = floorf(pz);
        wxa[s] = px - fx; wya[s] = py - fy; wza[s] = pz - fz;
        const uint32_t cx = (uint32_t)fx;
        const uint32_t cy = (uint32_t)fy;
        const uint32_t cz = (uint32_t)fz;

        const uint32_t hy0 = cy * PRIME_Y, hy1 = hy0 + PRIME_Y;
        const uint32_t hz0 = cz * PRIME_Z, hz1 = hz0 + PRIME_Z;
        const uint32_t hyz[4] = { hy0 ^ hz0, hy1 ^ hz0, hy0 ^ hz1, hy1 ^ hz1 };

        uint32_t sm = 0;
        if ((cx & 1u) == 0u) {
            // even cx: idx_b == idx_a^1 -> one aligned 8B pair load per corner
            #pragma unroll
            for (int q = 0; q < 4; ++q) {
                const uint32_t idx_a = (cx ^ hyz[q]) & (TABLE_SIZE - 1u);
                wreg[s][q] = *(const uint2*)(tab + (idx_a & ~1u));
                sm |= (idx_a & 1u) << q;
            }
        } else {
            #pragma unroll
            for (int q = 0; q < 4; ++q) {
                const uint32_t idx_a = (cx        ^ hyz[q]) & (TABLE_SIZE - 1u);
                const uint32_t idx_b = ((cx + 1u) ^ hyz[q]) & (TABLE_SIZE - 1u);
                wreg[s][q].x = tab[idx_a];
                wreg[s][q].y = tab[idx_b];
            }
        }
        swp[s] = sm;
    }

    // branchless consume (first use of wreg waits on the outstanding loads)
    #pragma unroll
    for (int s = 0; s < 2; ++s) {
        const float wx = wxa[s], wy = wya[s], wz = wza[s];
        const float wx0 = 1.0f - wx, wy0 = 1.0f - wy, wz0 = 1.0f - wz;
        float f0 = 0.0f, f1 = 0.0f;
        #pragma unroll
        for (int q = 0; q < 4; ++q) {
            const bool sw = (swp[s] >> q) & 1u;
            const uint32_t wa = sw ? wreg[s][q].y : wreg[s][q].x;
            const uint32_t wb = sw ? wreg[s][q].x : wreg[s][q].y;
            const float2 ca = unpk16(wa);
            const float2 cb = unpk16(wb);
            const float yf = (q & 1) ? wy : wy0;
            const float zf = (q & 2) ? wz : wz0;
            const float wgt_a = (wx0 * yf) * zf;
            const float wgt_b = (wx  * yf) * zf;
            f0 = fmaf(wgt_a, ca.x, f0);
            f1 = fmaf(wgt_a, ca.y, f1);
            f0 = fmaf(wgt_b, cb.x, f0);
            f1 = fmaf(wgt_b, cb.y, f1);
        }
        union { _Float16 h[2]; uint32_t u; } pk;
        pk.h[0] = (_Float16)(f0 * 256.0f);
        pk.h[1] = (_Float16)(f1 * 256.0f);
        __builtin_nontemporal_store(pk.u, a_ws2 + (size_t)l * n + pp[s]);
    }
}

// ---------- tier-B encode: f32 tables (fallback for small workspace) -----
__global__ __launch_bounds__(256, 8)
void encode_kernel(const float4* __restrict__ xs4,        // [N] sorted
                   const float* __restrict__ tables,      // [16, T, 2]
                   const float* __restrict__ resolutions, // [16]
                   uint32_t* __restrict__ a_ws2,          // [16][N] 2xf16 x256
                   int n)
{
    const int l = blockIdx.y;
    int p = blockIdx.x * blockDim.x + threadIdx.x;
    if (p >= n) p = n - 1;

    const float4 xv = xs4[p];
    const float x0 = xv.x * 0.5f + 0.5f;
    const float x1 = xv.y * 0.5f + 0.5f;
    const float x2 = xv.z * 0.5f + 0.5f;

    const float res = resolutions[l];
    const float px = x0 * res, py = x1 * res, pz = x2 * res;
    const float fx = floorf(px), fy = floorf(py), fz = floorf(pz);
    const float wx = px - fx, wy = py - fy, wz = pz - fz;
    const uint32_t cx = (uint32_t)fx;
    const uint32_t cy = (uint32_t)fy;
    const uint32_t cz = (uint32_t)fz;

    const uint32_t hy0 = cy * PRIME_Y, hy1 = hy0 + PRIME_Y;
    const uint32_t hz0 = cz * PRIME_Z, hz1 = hz0 + PRIME_Z;

    const float wx0 = 1.0f - wx, wy0 = 1.0f - wy, wz0 = 1.0f - wz;

    const float* __restrict__ tab = tables + (size_t)l * (size_t)TABLE_SIZE * 2u;

    const uint32_t hyz[4] = { hy0 ^ hz0, hy1 ^ hz0, hy0 ^ hz1, hy1 ^ hz1 };

    float2 cva[4], cvb[4];

    if ((cx & 1u) == 0u) {
        #pragma unroll
        for (int q = 0; q < 4; ++q) {
            const uint32_t idx_a = (cx ^ hyz[q]) & (TABLE_SIZE - 1u);
            const uint32_t base  = idx_a & ~1u;
            const float4 f4 = *(const float4*)(tab + 2u * base);
            const bool hi = (idx_a & 1u) != 0u;
            cva[q] = hi ? make_float2(f4.z, f4.w) : make_float2(f4.x, f4.y);
            cvb[q] = hi ? make_float2(f4.x, f4.y) : make_float2(f4.z, f4.w);
        }
    } else {
        const uint32_t hx0 = cx, hx1 = cx + 1u;
        #pragma unroll
        for (int q = 0; q < 4; ++q) {
            const uint32_t idx_a = (hx0 ^ hyz[q]) & (TABLE_SIZE - 1u);
            const uint32_t idx_b = (hx1 ^ hyz[q]) & (TABLE_SIZE - 1u);
            cva[q] = *(const float2*)(tab + 2u * idx_a);
            cvb[q] = *(const float2*)(tab + 2u * idx_b);
        }
    }

    float f0 = 0.0f, f1 = 0.0f;
    #pragma unroll
    for (int q = 0; q < 4; ++q) {
        const float yf = (q & 1) ? wy : wy0;
        const float zf = (q & 2) ? wz : wz0;
        const float wgt_a = (wx0 * yf) * zf;
        const float wgt_b = (wx  * yf) * zf;
        f0 = fmaf(wgt_a, cva[q].x, f0);
        f1 = fmaf(wgt_a, cva[q].y, f1);
        f0 = fmaf(wgt_b, cvb[q].x, f0);
        f1 = fmaf(wgt_b, cvb[q].y, f1);
    }

    union { _Float16 h[2]; uint32_t u; } pk;
    pk.h[0] = (_Float16)(f0 * 256.0f);
    pk.h[1] = (_Float16)(f1 * 256.0f);
    __builtin_nontemporal_store(pk.u, a_ws2 + (size_t)l * n + p);
}

// ============================ MFMA MLP ============================
// Layer-1 -> layer-2 handoff now goes through PACKED f16 LDS:
//  - activations stored as f16 pairs in a [point][channel] layout,
//    row stride 36 u32 (144B = 16B-aligned, banks perfectly balanced for
//    the b128 reads: each bank serves exactly 8 lanes = BW floor);
//  - b2h rebuild: ONE ds_read_b128 per half (was 8x ds_read_u16 + 8 cvt);
//  - stores: 8x b32 packed (was 16x b32 f32).
// Precision identical: same single RNE f32->f16 conversion, moved before
// the store. __threadfence_block removed (myl is wave-private; same-wave
// LDS RAW is ordered by lgkmcnt tracking).
#define MLP_WSTRIDE 36            // u32 per point-row (32 data + 4 pad)
#define MLP_WREG    (16 * MLP_WSTRIDE)   // 576 u32 per wave
__global__ __launch_bounds__(256, 2)
void mlp_mfma_kernel(const uint32_t* __restrict__ a_ws2, // [16][N] 2xf16 x256
                     const float* __restrict__ W1,
                     const float* __restrict__ b1,
                     const float* __restrict__ W2,
                     const float* __restrict__ b2,
                     const float* __restrict__ W3,
                     const float* __restrict__ b3,
                     float* __restrict__ outs,           // [N] sorted order
                     int n)
{
    __shared__ uint32_t ldsw[4 * MLP_WREG + 192];   // 4 waves act + 192 f32 bias
    float* __restrict__ biasf = (float*)&ldsw[4 * MLP_WREG];

    const int lane    = threadIdx.x & 63;
    const int wave_id = threadIdx.x >> 6;
    const int m       = lane & 15;
    const int q       = lane >> 4;
    uint32_t* __restrict__ myl = &ldsw[wave_id * MLP_WREG];

    if (threadIdx.x < 64) {
        biasf[threadIdx.x]       = 256.0f * b1[threadIdx.x];
        biasf[64 + threadIdx.x]  = 256.0f * b2[threadIdx.x];
        biasf[128 + threadIdx.x] = W3[threadIdx.x];
    }

    const float b3s = b3[0];

    v8h a1[4];
    #pragma unroll
    for (int t = 0; t < 4; ++t)
        #pragma unroll
        for (int j = 0; j < 8; ++j)
            a1[t][j] = (_Float16)W1[(8 * q + j) * 64 + 16 * t + m];

    v8h a2[2][4];
    #pragma unroll
    for (int c = 0; c < 2; ++c)
        #pragma unroll
        for (int t = 0; t < 4; ++t)
            #pragma unroll
            for (int j = 0; j < 8; ++j)
                a2[c][t][j] = (_Float16)W2[(32 * c + 8 * q + j) * 64 + 16 * t + m];

    __syncthreads();   // bias region ready

    const int nt = (n + 15) >> 4;
    const int stride = gridDim.x * 4;
    const int gw = blockIdx.x * 4 + wave_id;
    if (gw >= nt) return;

    union BF { uint32_t w[4]; v8h h; };

    v8h bh;
    {
        const int p0 = gw * 16;
        const int pr = (p0 + m < n) ? (p0 + m) : (n - 1);
        BF ub;
        #pragma unroll
        for (int lv = 0; lv < 4; ++lv)
            ub.w[lv] = __builtin_nontemporal_load(
                a_ws2 + (size_t)(4 * q + lv) * n + pr);
        bh = ub.h;
    }

    for (int tile = gw; tile < nt; tile += stride) {
        const int p0 = tile * 16;

        v8h bhn = bh;
        const int nx = tile + stride;
        if (nx < nt) {
            const int p0n = nx * 16;
            const int prn = (p0n + m < n) ? (p0n + m) : (n - 1);
            BF ub;
            #pragma unroll
            for (int lv = 0; lv < 4; ++lv)
                ub.w[lv] = __builtin_nontemporal_load(
                    a_ws2 + (size_t)(4 * q + lv) * n + prn);
            bhn = ub.h;
        }

        v4f acc1[4];
        #pragma unroll
        for (int t = 0; t < 4; ++t) {
            acc1[t] = *(const v4f*)&biasf[16 * t + 4 * q];   // bcast read
            acc1[t] = __builtin_amdgcn_mfma_f32_16x16x32_f16(a1[t], bh, acc1[t], 0, 0, 0);
        }

        // relu + pack to f16 pairs, store to [point m][channel] LDS rows
        #pragma unroll
        for (int t = 0; t < 4; ++t) {
            union { _Float16 h[2]; uint32_t u; } pkA, pkB;
            pkA.h[0] = (_Float16)fmaxf(acc1[t][0], 0.0f);
            pkA.h[1] = (_Float16)fmaxf(acc1[t][1], 0.0f);
            pkB.h[0] = (_Float16)fmaxf(acc1[t][2], 0.0f);
            pkB.h[1] = (_Float16)fmaxf(acc1[t][3], 0.0f);
            uint32_t* wp = myl + m * MLP_WSTRIDE + 8 * t + 2 * q;
            wp[0] = pkA.u;
            wp[1] = pkB.u;
        }

        v8h b2h[2];
        #pragma unroll
        for (int c = 0; c < 2; ++c)
            b2h[c] = *(const v8h*)(myl + m * MLP_WSTRIDE + 16 * c + 4 * q);

        v4f acc2[4];
        #pragma unroll
        for (int t = 0; t < 4; ++t) {
            acc2[t] = *(const v4f*)&biasf[64 + 16 * t + 4 * q];
            acc2[t] = __builtin_amdgcn_mfma_f32_16x16x32_f16(a2[0][t], b2h[0], acc2[t], 0, 0, 0);
            acc2[t] = __builtin_amdgcn_mfma_f32_16x16x32_f16(a2[1][t], b2h[1], acc2[t], 0, 0, 0);
        }

        float partial = 0.0f;
        #pragma unroll
        for (int t = 0; t < 4; ++t) {
            const v4f w3q = *(const v4f*)&biasf[128 + 16 * t + 4 * q];
            #pragma unroll
            for (int r = 0; r < 4; ++r)
                partial = fmaf(fmaxf(acc2[t][r], 0.0f), w3q[r], partial);
        }

        partial += __shfl_xor(partial, 16);
        partial += __shfl_xor(partial, 32);

        if (q == 0 && p0 + m < n)
            outs[p0 + m] = partial * (1.0f / 256.0f) + b3s;

        bh = bhn;
    }
}

// out[i] = outs[rank_inv[i]] : coalesced read of rank_inv, coalesced write of
// out, random 4B gather from the 8MB outs (read-only -> replicates in L2s).
__global__ __launch_bounds__(256)
void unscatter_kernel(const float* __restrict__ outs,
                      const int* __restrict__ rank_inv,
                      float* __restrict__ out, int n) {
    const int i = blockIdx.x * blockDim.x + threadIdx.x;
    if (i < n) out[i] = outs[rank_inv[i]];
}

// ==================== Fallback: fused kernel ====================
__global__ __launch_bounds__(256, 4)
void hashgrid_mlp_fused(const float* __restrict__ x,
                        const float* __restrict__ tables,
                        const float* __restrict__ resolutions,
                        const float* __restrict__ W1,
                        const float* __restrict__ b1,
                        const float* __restrict__ W2,
                        const float* __restrict__ b2,
                        const float* __restrict__ W3,
                        const float* __restrict__ b3,
                        float* __restrict__ out,
                        int n)
{
    const int i  = blockIdx.x * blockDim.x + threadIdx.x;
    const int ip = (i < n) ? i : (n - 1);

    const float x0 = x[3 * ip + 0] * 0.5f + 0.5f;
    const float x1 = x[3 * ip + 1] * 0.5f + 0.5f;
    const float x2 = x[3 * ip + 2] * 0.5f + 0.5f;

    float h1[64];
    #pragma unroll
    for (int j = 0; j < 64; ++j) h1[j] = b1[j];

    #pragma unroll
    for (int l = 0; l < N_LEVELS; ++l) {
        const float res = resolutions[l];
        const float px = x0 * res, py = x1 * res, pz = x2 * res;
        const float fx = floorf(px), fy = floorf(py), fz = floorf(pz);
        const float wx = px - fx, wy = py - fy, wz = pz - fz;
        const uint32_t cx = (uint32_t)fx;
        const uint32_t cy = (uint32_t)fy;
        const uint32_t cz = (uint32_t)fz;
        const uint32_t hx0 = cx,           hx1 = cx + 1u;
        const uint32_t hy0 = cy * PRIME_Y, hy1 = hy0 + PRIME_Y;
        const uint32_t hz0 = cz * PRIME_Z, hz1 = hz0 + PRIME_Z;
        const float wx0 = 1.0f - wx, wy0 = 1.0f - wy, wz0 = 1.0f - wz;
        const float* __restrict__ tab = tables + (size_t)l * (size_t)TABLE_SIZE * 2u;

        float f0 = 0.0f, f1 = 0.0f;
        #pragma unroll
        for (int c = 0; c < 8; ++c) {
            const uint32_t h = ((c & 1) ? hx1 : hx0) ^
                               ((c & 2) ? hy1 : hy0) ^
                               ((c & 4) ? hz1 : hz0);
            const uint32_t idx = h & (TABLE_SIZE - 1u);
            const float2 fv = *(const float2*)(tab + 2u * idx);
            const float wgt = ((c & 1) ? wx : wx0) *
                              ((c & 2) ? wy : wy0) *
                              ((c & 4) ? wz : wz0);
            f0 = fmaf(wgt, fv.x, f0);
            f1 = fmaf(wgt, fv.y, f1);
        }
        const float* __restrict__ w1a = W1 + (2 * l + 0) * 64;
        const float* __restrict__ w1b = W1 + (2 * l + 1) * 64;
        #pragma unroll
        for (int j = 0; j < 64; ++j)
            h1[j] = fmaf(f1, w1b[j], fmaf(f0, w1a[j], h1[j]));
    }

    #pragma unroll
    for (int j = 0; j < 64; ++j) h1[j] = fmaxf(h1[j], 0.0f);

    float accum = b3[0];
    #pragma unroll
    for (int half = 0; half < 2; ++half) {
        float h2[32];
        #pragma unroll
        for (int j = 0; j < 32; ++j) h2[j] = b2[half * 32 + j];
        #pragma unroll
        for (int k = 0; k < 64; ++k) {
            const float hk = h1[k];
            const float* __restrict__ w2row = W2 + k * 64 + half * 32;
            #pragma unroll
            for (int j = 0; j < 32; ++j)
                h2[j] = fmaf(hk, w2row[j], h2[j]);
        }
        #pragma unroll
        for (int j = 0; j < 32; ++j)
            accum = fmaf(fmaxf(h2[j], 0.0f), W3[half * 32 + j], accum);
    }
    out[ip] = accum;
}

extern "C" void kernel_launch(void* const* d_in, const int* in_sizes, int n_in,
                              void* d_out, int out_size, void* d_ws, size_t ws_size,
                              hipStream_t stream) {
    const float* x           = (const float*)d_in[0];
    const float* tables      = (const float*)d_in[1];
    const float* resolutions = (const float*)d_in[2];
    const float* W1          = (const float*)d_in[3];
    const float* b1          = (const float*)d_in[4];
    const float* W2          = (const float*)d_in[5];
    const float* b2          = (const float*)d_in[6];
    const float* W3          = (const float*)d_in[7];
    const float* b3          = (const float*)d_in[8];
    float* out               = (float*)d_out;

    const int n = out_size;  // 2,000,000
    const int block = 256;
    const int grid_pts = (n + block - 1) / block;
    const int chunk = (n + SORT_B - 1) / SORT_B;
    const int half = (n + 1) / 2;
    const int grid_half = (half + block - 1) / block;

    // ---- workspace layout ----
    // a_ws2 (128 MB) is written only by encode, AFTER the sort finishes, so
    // the sort's metadata (g_hist 32 MB + g_part 32 MB) aliases into it.
    // tab16 (32 MB) sits at the end so tier B (no-f16-table) still fits
    // smaller workspaces.
    size_t off = 0;
    #define CARVE(bytes) (off = (off + 255) & ~(size_t)255, off += (bytes), off - (bytes))
    const size_t aws_off   = CARVE((size_t)16 * n * sizeof(uint32_t)); // 128 MB
    const size_t xs_off    = CARVE((size_t)n * sizeof(float4));        //  32 MB
    const size_t rank_off  = CARVE((size_t)n * sizeof(int));           //   8 MB
    const size_t outs_off  = CARVE((size_t)n * sizeof(float));         //   8 MB
    const size_t tot_off   = CARVE((size_t)NB * sizeof(uint32_t));
    const size_t base_off  = CARVE((size_t)NB * sizeof(uint32_t));
    const size_t total_ws_B = off;
    const size_t tab16_off = CARVE((size_t)N_LEVELS * TABLE_SIZE * sizeof(uint32_t)); // 32 MB
    const size_t total_ws_A = off;
    #undef CARVE

    if (ws_size >= total_ws_B) {
        const bool f16tab = (ws_size >= total_ws_A);
        char* ws = (char*)d_ws;
        uint32_t* a_ws2  = (uint32_t*)(ws + aws_off);
        uint32_t* g_hist = (uint32_t*)(ws + aws_off);                          // alias
        uint32_t* g_part = (uint32_t*)(ws + aws_off + (size_t)SORT_B * NB * 4);// alias
        float4*   xs4    = (float4*)(ws + xs_off);
        int*      rank   = (int*)(ws + rank_off);
        float*    outs   = (float*)(ws + outs_off);
        uint32_t* totals = (uint32_t*)(ws + tot_off);
        uint32_t* base   = (uint32_t*)(ws + base_off);
        uint32_t* tab16  = (uint32_t*)(ws + tab16_off);

        // hist (+ folded table cvt when tier-A)
        const int hist_grid = SORT_B + (f16tab ? CVT_B : 0);
        hist_cvt_kernel<<<hist_grid, SORT_T, 0, stream>>>(
            x, g_hist, n, chunk, tables, f16tab ? tab16 : (uint32_t*)nullptr);
        scan_cols_kernel<<<NB / 256, block, 0, stream>>>(g_hist, g_part, totals);
        scan32k_kernel<<<1, 1024, 0, stream>>>(totals, base);
        scatter_kernel<<<SORT_B, SORT_T, 0, stream>>>(
            x, base, g_part, xs4, rank, n, chunk);

        if (f16tab) {
            dim3 grid_enc(grid_half, N_LEVELS);   // 2 points per thread
            encode_f16_kernel<<<grid_enc, block, 0, stream>>>(
                xs4, tab16, resolutions, a_ws2, n, half);
        } else {
            dim3 grid_enc(grid_pts, N_LEVELS);
            encode_kernel<<<grid_enc, block, 0, stream>>>(
                xs4, tables, resolutions, a_ws2, n);
        }
        mlp_mfma_kernel<<<1024, block, 0, stream>>>(a_ws2, W1, b1, W2, b2, W3, b3,
                                                    outs, n);
        unscatter_kernel<<<grid_pts, block, 0, stream>>>(outs, rank, out, n);
    } else {
        hashgrid_mlp_fused<<<grid_pts, block, 0, stream>>>(
            x, tables, resolutions, W1, b1, W2, b2, W3, b3, out, n);
    }
}